// Round 1
// baseline (3757.406 us; speedup 1.0000x reference)
//
#include <hip/hip_runtime.h>
#include <hip/hip_bf16.h>

typedef __attribute__((ext_vector_type(8))) short bf16x8;
typedef __attribute__((ext_vector_type(4))) float f32x4;
typedef __hip_bfloat16 bf16;

constexpr int DM   = 1024;
constexpr int NH   = 16;
constexpr int HD   = 64;
constexpr int FF   = 4096;
constexpr int NL   = 6;
constexpr int NB   = 8;
constexpr int SEQL = 512;
constexpr int NTOK = NB * SEQL;   // 4096

// ---------------- async global->LDS (16B) ----------------
__device__ __forceinline__ void gl_lds16(const void* g, void* l) {
  __builtin_amdgcn_global_load_lds(
      (const __attribute__((address_space(1))) unsigned int*)g,
      (__attribute__((address_space(3))) unsigned int*)l, 16, 0, 0);
}

// ---------------- weight transpose + f32->bf16 ----------------
// src: [R][C] f32 (batch z), dst: [C][R] bf16
__global__ __launch_bounds__(256) void transpose_cvt(const float* __restrict__ src,
                                                     bf16* __restrict__ dst,
                                                     int R, int C) {
  __shared__ float tile[32][33];
  size_t mo = (size_t)blockIdx.z * R * C;
  src += mo; dst += mo;
  int c0 = blockIdx.x * 32, r0 = blockIdx.y * 32;
  int tx = threadIdx.x, ty = threadIdx.y;   // 32 x 8
  #pragma unroll
  for (int j = 0; j < 4; ++j)
    tile[ty + 8*j][tx] = src[(size_t)(r0 + ty + 8*j) * C + c0 + tx];
  __syncthreads();
  #pragma unroll
  for (int j = 0; j < 4; ++j)
    dst[(size_t)(c0 + ty + 8*j) * R + r0 + tx] = __float2bfloat16(tile[tx][ty + 8*j]);
}

__global__ __launch_bounds__(256) void cvt_bf16(const float* __restrict__ s,
                                                bf16* __restrict__ d) {
  size_t i = (size_t)blockIdx.x * 256 + threadIdx.x;
  float4 v = ((const float4*)s)[i];
  union { bf16 h[4]; uint2 u; } t;
  t.h[0] = __float2bfloat16(v.x); t.h[1] = __float2bfloat16(v.y);
  t.h[2] = __float2bfloat16(v.z); t.h[3] = __float2bfloat16(v.w);
  *(uint2*)(d + i * 4) = t.u;
}

// ---------------- embedding + positional encoding ----------------
__global__ __launch_bounds__(256) void embed_pe(const int* __restrict__ tok,
                                                const float* __restrict__ table,
                                                float* __restrict__ x) {
  int t = blockIdx.x;               // token index (b*512+s)
  int s = t & (SEQL - 1);
  int tk = tok[t];
  int d = threadIdx.x * 4;
  float4 e = *(const float4*)(table + (size_t)tk * DM + d);
  float o[4] = {e.x, e.y, e.z, e.w};
  const float NEGC = -9.210340371976184f / 1024.0f;   // -ln(10000)/D
  #pragma unroll
  for (int i = 0; i < 4; ++i) {
    int dd = d + i;
    float div = __expf((float)(dd & ~1) * NEGC);
    float arg = (float)s * div;
    float pe = (dd & 1) ? cosf(arg) : sinf(arg);
    o[i] = o[i] * 32.0f + pe;       // sqrt(1024)=32
  }
  float4 ov = {o[0], o[1], o[2], o[3]};
  *(float4*)(x + (size_t)t * DM + d) = ov;
}

// ---------------- layernorm (row=1024), out bf16 or f32 ----------------
template<int OUTF32>
__global__ __launch_bounds__(256) void ln_kernel(const float* __restrict__ x,
                                                 const float* __restrict__ g,
                                                 const float* __restrict__ bb,
                                                 bf16* __restrict__ ob,
                                                 float* __restrict__ of) {
  int row = blockIdx.x;
  int tid = threadIdx.x;
  const float4 v = *(const float4*)(x + (size_t)row * DM + tid * 4);
  float s = v.x + v.y + v.z + v.w;
  #pragma unroll
  for (int o = 32; o; o >>= 1) s += __shfl_down(s, o);
  __shared__ float red[8];
  int wv = tid >> 6, ln = tid & 63;
  if (!ln) red[wv] = s;
  __syncthreads();
  float mean = (red[0] + red[1] + red[2] + red[3]) * (1.0f / DM);
  float d0 = v.x - mean, d1 = v.y - mean, d2 = v.z - mean, d3 = v.w - mean;
  float s2 = d0*d0 + d1*d1 + d2*d2 + d3*d3;
  #pragma unroll
  for (int o = 32; o; o >>= 1) s2 += __shfl_down(s2, o);
  if (!ln) red[4 + wv] = s2;
  __syncthreads();
  float var = (red[4] + red[5] + red[6] + red[7]) * (1.0f / DM);
  float rs = rsqrtf(var + 1e-5f);
  float4 gg = *(const float4*)(g + tid * 4);
  float4 bv = *(const float4*)(bb + tid * 4);
  float y0 = d0 * rs * gg.x + bv.x;
  float y1 = d1 * rs * gg.y + bv.y;
  float y2 = d2 * rs * gg.z + bv.z;
  float y3 = d3 * rs * gg.w + bv.w;
  if (OUTF32) {
    float4 ov = {y0, y1, y2, y3};
    *(float4*)(of + (size_t)row * DM + tid * 4) = ov;
  } else {
    union { bf16 h[4]; uint2 u; } t;
    t.h[0] = __float2bfloat16(y0); t.h[1] = __float2bfloat16(y1);
    t.h[2] = __float2bfloat16(y2); t.h[3] = __float2bfloat16(y3);
    *(uint2*)(ob + (size_t)row * DM + tid * 4) = t.u;
  }
}

// ---------------- GEMM: C[M,N] = A[M,K] x Bt[N,K]^T (+epilogue) ----------------
// EPI 0: bf16 out, +bias[col]
// EPI 1: bf16 out, +bias[col], relu
// EPI 2: bf16 out, +bias[row]          (used to produce V^T directly)
// EPI 3: f32   Cf[row,col] += acc + bias[col]   (residual accumulate)
template<int EPI>
__global__ __launch_bounds__(256) void gemm_bt(const bf16* __restrict__ A,
                                               const bf16* __restrict__ Bt,
                                               const float* __restrict__ bias,
                                               bf16* __restrict__ Cb,
                                               float* __restrict__ Cf,
                                               int M, int N, int K) {
  __shared__ bf16 As[128 * 32];
  __shared__ bf16 Bs[128 * 32];
  int tid = threadIdx.x;
  int wave = tid >> 6, lane = tid & 63;
  int l4 = lane & 15, lhi = lane >> 4;
  int wr = wave >> 1, wc = wave & 1;            // 2x2 waves, 64x64 each
  int brow = blockIdx.y * 128, bcol = blockIdx.x * 128;
  f32x4 acc[4][4] = {};
  int srow = lane >> 2;                          // 0..15
  int scol = (lane & 3) * 8;                     // bf16 elem offset
  for (int k0 = 0; k0 < K; k0 += 32) {
    __syncthreads();
    #pragma unroll
    for (int i = 0; i < 2; ++i) {
      int rb = i * 64 + wave * 16;               // wave-uniform row base
      gl_lds16(A  + (size_t)(brow + rb + srow) * K + k0 + scol, &As[rb * 32]);
      gl_lds16(Bt + (size_t)(bcol + rb + srow) * K + k0 + scol, &Bs[rb * 32]);
    }
    __syncthreads();
    bf16x8 af[4], bfv[4];
    #pragma unroll
    for (int m = 0; m < 4; ++m)
      af[m] = *(const bf16x8*)&As[(wr * 64 + m * 16 + l4) * 32 + lhi * 8];
    #pragma unroll
    for (int n = 0; n < 4; ++n)
      bfv[n] = *(const bf16x8*)&Bs[(wc * 64 + n * 16 + l4) * 32 + lhi * 8];
    #pragma unroll
    for (int m = 0; m < 4; ++m)
      #pragma unroll
      for (int n = 0; n < 4; ++n)
        acc[m][n] = __builtin_amdgcn_mfma_f32_16x16x32_bf16(af[m], bfv[n], acc[m][n], 0, 0, 0);
  }
  #pragma unroll
  for (int m = 0; m < 4; ++m) {
    int row0 = brow + wr * 64 + m * 16 + lhi * 4;
    #pragma unroll
    for (int n = 0; n < 4; ++n) {
      int col = bcol + wc * 64 + n * 16 + l4;
      #pragma unroll
      for (int r = 0; r < 4; ++r) {
        int row = row0 + r;
        float v = acc[m][n][r];
        if (EPI == 0) {
          v += bias[col];
          Cb[(size_t)row * N + col] = __float2bfloat16(v);
        } else if (EPI == 1) {
          v += bias[col];
          v = fmaxf(v, 0.0f);
          Cb[(size_t)row * N + col] = __float2bfloat16(v);
        } else if (EPI == 2) {
          v += bias[row];
          Cb[(size_t)row * N + col] = __float2bfloat16(v);
        } else {
          v += bias[col];
          size_t idx = (size_t)row * N + col;
          Cf[idx] = Cf[idx] + v;
        }
      }
    }
  }
}

// ---------------- fused attention ----------------
// q: [NTOK, DM] bf16; k: [NTOK, DM] bf16; vT: [DM, NTOK] bf16; out: [NTOK, DM] bf16
// grid: (SEQL/64, NB*NH); 4 waves, wave owns 16 q-rows.
template<int CAUSAL>
__global__ __launch_bounds__(256, 2) void attn_kernel(const bf16* __restrict__ qg,
                                                      const bf16* __restrict__ kg,
                                                      const bf16* __restrict__ vtg,
                                                      bf16* __restrict__ og) {
  __shared__ bf16 P[4][16][520];   // per-wave P rows, padded (2-way-free banks)
  int qblk = blockIdx.x;
  int bh = blockIdx.y;
  int b = bh >> 4, h = bh & 15;
  int wave = threadIdx.x >> 6, lane = threadIdx.x & 63;
  int l4 = lane & 15, lhi = lane >> 4;

  bf16x8 qa[2];
  {
    size_t qrow = (size_t)(b * SEQL + qblk * 64 + wave * 16 + l4);
    #pragma unroll
    for (int kk = 0; kk < 2; ++kk)
      qa[kk] = *(const bf16x8*)&qg[qrow * DM + h * HD + kk * 32 + lhi * 8];
  }
  // QK^T: scores[16 q][512 keys] per wave
  f32x4 acc[32] = {};
  #pragma unroll
  for (int n = 0; n < 32; ++n) {
    #pragma unroll
    for (int kk = 0; kk < 2; ++kk) {
      bf16x8 kf = *(const bf16x8*)&kg[(size_t)(b * SEQL + n * 16 + l4) * DM + h * HD + kk * 32 + lhi * 8];
      acc[n] = __builtin_amdgcn_mfma_f32_16x16x32_bf16(qa[kk], kf, acc[n], 0, 0, 0);
    }
  }
  // softmax (row-wise over 512), C layout: col=n*16+l4, row=lhi*4+r
  int qloc = qblk * 64 + wave * 16 + lhi * 4;
  #pragma unroll
  for (int r = 0; r < 4; ++r) {
    float mx = -3.0e38f;
    #pragma unroll
    for (int n = 0; n < 32; ++n) {
      float sv = acc[n][r] * 0.125f;
      if (CAUSAL && (n * 16 + l4 > qloc + r)) sv = -3.0e38f;
      acc[n][r] = sv;
      mx = fmaxf(mx, sv);
    }
    #pragma unroll
    for (int o = 1; o < 16; o <<= 1) mx = fmaxf(mx, __shfl_xor(mx, o));
    float sum = 0.0f;
    #pragma unroll
    for (int n = 0; n < 32; ++n) {
      float p = __expf(acc[n][r] - mx);
      acc[n][r] = p;
      sum += p;
    }
    #pragma unroll
    for (int o = 1; o < 16; o <<= 1) sum += __shfl_xor(sum, o);
    float rcp = 1.0f / sum;
    #pragma unroll
    for (int n = 0; n < 32; ++n)
      P[wave][lhi * 4 + r][n * 16 + l4] = __float2bfloat16(acc[n][r] * rcp);
  }
  __syncthreads();
  // PV: out[16 q][64 d] per wave; A-frags from P LDS, B-frags from vT global
  f32x4 oacc[4] = {};
  #pragma unroll
  for (int ks = 0; ks < 16; ++ks) {
    bf16x8 pa = *(const bf16x8*)&P[wave][l4][ks * 32 + lhi * 8];
    #pragma unroll
    for (int n = 0; n < 4; ++n) {
      bf16x8 vf = *(const bf16x8*)&vtg[(size_t)(h * HD + n * 16 + l4) * NTOK + b * SEQL + ks * 32 + lhi * 8];
      oacc[n] = __builtin_amdgcn_mfma_f32_16x16x32_bf16(pa, vf, oacc[n], 0, 0, 0);
    }
  }
  size_t orow = (size_t)(b * SEQL + qblk * 64 + wave * 16 + lhi * 4);
  #pragma unroll
  for (int n = 0; n < 4; ++n)
    #pragma unroll
    for (int r = 0; r < 4; ++r)
      og[(orow + r) * DM + h * HD + n * 16 + l4] = __float2bfloat16(oacc[n][r]);
}

// ---------------- host ----------------
extern "C" void kernel_launch(void* const* d_in, const int* in_sizes, int n_in,
                              void* d_out, int out_size, void* d_ws, size_t ws_size,
                              hipStream_t stream) {
  (void)in_sizes; (void)n_in; (void)out_size;
  const float* enc   = (const float*)d_in[0];
  const int*   toks  = (const int*)  d_in[1];
  const float* table = (const float*)d_in[4];
  const float* sa_w  = (const float*)d_in[5];
  const float* sa_b  = (const float*)d_in[6];
  const float* ca_w  = (const float*)d_in[7];
  const float* ca_b  = (const float*)d_in[8];
  const float* f1w   = (const float*)d_in[9];
  const float* f1b   = (const float*)d_in[10];
  const float* f2w   = (const float*)d_in[11];
  const float* f2b   = (const float*)d_in[12];
  const float* lng   = (const float*)d_in[13];
  const float* lnbp  = (const float*)d_in[14];
  const float* fg    = (const float*)d_in[15];
  const float* fbp   = (const float*)d_in[16];
  float* outp = (float*)d_out;

  char* base = (char*)d_ws;
  size_t off = 0;
  auto alloc = [&](size_t nbytes) -> char* {
    char* p = base + off;
    off += (nbytes + 255) & ~(size_t)255;
    return p;
  };
  const size_t DDb = (size_t)DM * DM;
  bf16* wt_sa  = (bf16*)alloc((size_t)NL * 4 * DDb * 2);
  bf16* wt_ca  = (bf16*)alloc((size_t)NL * 4 * DDb * 2);
  bf16* wt_f1  = (bf16*)alloc((size_t)NL * FF * DM * 2);
  bf16* wt_f2  = (bf16*)alloc((size_t)NL * FF * DM * 2);
  bf16* encb   = (bf16*)alloc((size_t)NTOK * DM * 2);
  bf16* hbuf   = (bf16*)alloc((size_t)NTOK * DM * 2);
  bf16* qbuf   = (bf16*)alloc((size_t)NTOK * DM * 2);
  bf16* kbuf   = (bf16*)alloc((size_t)NTOK * DM * 2);
  bf16* vtbuf  = (bf16*)alloc((size_t)NTOK * DM * 2);
  bf16* aobuf  = (bf16*)alloc((size_t)NTOK * DM * 2);
  bf16* kebuf  = (bf16*)alloc((size_t)NTOK * DM * 2);
  bf16* vtebuf = (bf16*)alloc((size_t)NTOK * DM * 2);
  bf16* h1buf  = (bf16*)alloc((size_t)NTOK * FF * 2);
  float* xbuf  = (float*)alloc((size_t)NTOK * DM * 4);
  if (off > ws_size) return;   // workspace too small -> clean failure

  dim3 tb(32, 8);
  transpose_cvt<<<dim3(DM/32, DM/32, NL*4), tb, 0, stream>>>(sa_w, wt_sa, DM, DM);
  transpose_cvt<<<dim3(DM/32, DM/32, NL*4), tb, 0, stream>>>(ca_w, wt_ca, DM, DM);
  transpose_cvt<<<dim3(FF/32, DM/32, NL),   tb, 0, stream>>>(f1w, wt_f1, DM, FF);
  transpose_cvt<<<dim3(DM/32, FF/32, NL),   tb, 0, stream>>>(f2w, wt_f2, FF, DM);
  cvt_bf16<<<(NTOK * DM / 4) / 256, 256, 0, stream>>>(enc, encb);
  embed_pe<<<NTOK, 256, 0, stream>>>(toks, table, xbuf);

  for (int l = 0; l < NL; ++l) {
    const bf16* wsa = wt_sa + (size_t)l * 4 * DDb;
    const bf16* wca = wt_ca + (size_t)l * 4 * DDb;
    const float* bsa = sa_b + (size_t)l * 4 * DM;
    const float* bca = ca_b + (size_t)l * 4 * DM;
    // ---- self-attention (pre-norm) ----
    ln_kernel<0><<<NTOK, 256, 0, stream>>>(xbuf, lng + (l*3+0)*DM, lnbp + (l*3+0)*DM, hbuf, nullptr);
    gemm_bt<0><<<dim3(DM/128, NTOK/128), 256, 0, stream>>>(hbuf, wsa + 0*DDb, bsa + 0*DM, qbuf, nullptr, NTOK, DM, DM);
    gemm_bt<0><<<dim3(DM/128, NTOK/128), 256, 0, stream>>>(hbuf, wsa + 1*DDb, bsa + 1*DM, kbuf, nullptr, NTOK, DM, DM);
    gemm_bt<2><<<dim3(NTOK/128, DM/128), 256, 0, stream>>>(wsa + 2*DDb, hbuf, bsa + 2*DM, vtbuf, nullptr, DM, NTOK, DM);
    attn_kernel<1><<<dim3(SEQL/64, NB*NH), 256, 0, stream>>>(qbuf, kbuf, vtbuf, aobuf);
    gemm_bt<3><<<dim3(DM/128, NTOK/128), 256, 0, stream>>>(aobuf, wsa + 3*DDb, bsa + 3*DM, nullptr, xbuf, NTOK, DM, DM);
    // ---- cross-attention (pre-norm) ----
    ln_kernel<0><<<NTOK, 256, 0, stream>>>(xbuf, lng + (l*3+1)*DM, lnbp + (l*3+1)*DM, hbuf, nullptr);
    gemm_bt<0><<<dim3(DM/128, NTOK/128), 256, 0, stream>>>(hbuf, wca + 0*DDb, bca + 0*DM, qbuf, nullptr, NTOK, DM, DM);
    gemm_bt<0><<<dim3(DM/128, NTOK/128), 256, 0, stream>>>(encb, wca + 1*DDb, bca + 1*DM, kebuf, nullptr, NTOK, DM, DM);
    gemm_bt<2><<<dim3(NTOK/128, DM/128), 256, 0, stream>>>(wca + 2*DDb, encb, bca + 2*DM, vtebuf, nullptr, DM, NTOK, DM);
    attn_kernel<0><<<dim3(SEQL/64, NB*NH), 256, 0, stream>>>(qbuf, kebuf, vtebuf, aobuf);
    gemm_bt<3><<<dim3(DM/128, NTOK/128), 256, 0, stream>>>(aobuf, wca + 3*DDb, bca + 3*DM, nullptr, xbuf, NTOK, DM, DM);
    // ---- FFN (pre-norm) ----
    ln_kernel<0><<<NTOK, 256, 0, stream>>>(xbuf, lng + (l*3+2)*DM, lnbp + (l*3+2)*DM, hbuf, nullptr);
    gemm_bt<1><<<dim3(FF/128, NTOK/128), 256, 0, stream>>>(hbuf, wt_f1 + (size_t)l*FF*DM, f1b + (size_t)l*FF, h1buf, nullptr, NTOK, FF, DM);
    gemm_bt<3><<<dim3(DM/128, NTOK/128), 256, 0, stream>>>(h1buf, wt_f2 + (size_t)l*FF*DM, f2b + (size_t)l*DM, nullptr, xbuf, NTOK, DM, FF);
  }
  ln_kernel<1><<<NTOK, 256, 0, stream>>>(xbuf, fg, fbp, nullptr, outp);
}

// Round 2
// 3511.092 us; speedup vs baseline: 1.0702x; 1.0702x over previous
//
#include <hip/hip_runtime.h>
#include <hip/hip_bf16.h>

typedef __attribute__((ext_vector_type(8))) short bf16x8;
typedef __attribute__((ext_vector_type(4))) float f32x4;
typedef __hip_bfloat16 bf16;

constexpr int DM   = 1024;
constexpr int NH   = 16;
constexpr int HD   = 64;
constexpr int FF   = 4096;
constexpr int NL   = 6;
constexpr int NB   = 8;
constexpr int SEQL = 512;
constexpr int NTOK = NB * SEQL;   // 4096

// ---------------- async global->LDS (16B) ----------------
__device__ __forceinline__ void gl_lds16(const void* g, void* l) {
  __builtin_amdgcn_global_load_lds(
      (const __attribute__((address_space(1))) unsigned int*)g,
      (__attribute__((address_space(3))) unsigned int*)l, 16, 0, 0);
}

// ---------------- weight transpose + f32->bf16 ----------------
// src: [R][C] f32 (batch z), dst: [C][R] bf16
__global__ __launch_bounds__(256) void transpose_cvt(const float* __restrict__ src,
                                                     bf16* __restrict__ dst,
                                                     int R, int C) {
  __shared__ float tile[32][33];
  size_t mo = (size_t)blockIdx.z * R * C;
  src += mo; dst += mo;
  int c0 = blockIdx.x * 32, r0 = blockIdx.y * 32;
  int tx = threadIdx.x, ty = threadIdx.y;   // 32 x 8
  #pragma unroll
  for (int j = 0; j < 4; ++j)
    tile[ty + 8*j][tx] = src[(size_t)(r0 + ty + 8*j) * C + c0 + tx];
  __syncthreads();
  #pragma unroll
  for (int j = 0; j < 4; ++j)
    dst[(size_t)(c0 + ty + 8*j) * R + r0 + tx] = __float2bfloat16(tile[tx][ty + 8*j]);
}

__global__ __launch_bounds__(256) void cvt_bf16(const float* __restrict__ s,
                                                bf16* __restrict__ d) {
  size_t i = (size_t)blockIdx.x * 256 + threadIdx.x;
  float4 v = ((const float4*)s)[i];
  union { bf16 h[4]; uint2 u; } t;
  t.h[0] = __float2bfloat16(v.x); t.h[1] = __float2bfloat16(v.y);
  t.h[2] = __float2bfloat16(v.z); t.h[3] = __float2bfloat16(v.w);
  *(uint2*)(d + i * 4) = t.u;
}

// ---------------- embedding + positional encoding ----------------
__global__ __launch_bounds__(256) void embed_pe(const int* __restrict__ tok,
                                                const float* __restrict__ table,
                                                float* __restrict__ x) {
  int t = blockIdx.x;               // token index (b*512+s)
  int s = t & (SEQL - 1);
  int tk = tok[t];
  int d = threadIdx.x * 4;
  float4 e = *(const float4*)(table + (size_t)tk * DM + d);
  float o[4] = {e.x, e.y, e.z, e.w};
  const float NEGC = -9.210340371976184f / 1024.0f;   // -ln(10000)/D
  #pragma unroll
  for (int i = 0; i < 4; ++i) {
    int dd = d + i;
    float div = __expf((float)(dd & ~1) * NEGC);
    float arg = (float)s * div;
    float pe = (dd & 1) ? cosf(arg) : sinf(arg);
    o[i] = o[i] * 32.0f + pe;       // sqrt(1024)=32
  }
  float4 ov = {o[0], o[1], o[2], o[3]};
  *(float4*)(x + (size_t)t * DM + d) = ov;
}

// ---------------- layernorm (row=1024), out bf16 or f32 ----------------
template<int OUTF32>
__global__ __launch_bounds__(256) void ln_kernel(const float* __restrict__ x,
                                                 const float* __restrict__ g,
                                                 const float* __restrict__ bb,
                                                 bf16* __restrict__ ob,
                                                 float* __restrict__ of) {
  int row = blockIdx.x;
  int tid = threadIdx.x;
  const float4 v = *(const float4*)(x + (size_t)row * DM + tid * 4);
  float s = v.x + v.y + v.z + v.w;
  #pragma unroll
  for (int o = 32; o; o >>= 1) s += __shfl_down(s, o);
  __shared__ float red[8];
  int wv = tid >> 6, ln = tid & 63;
  if (!ln) red[wv] = s;
  __syncthreads();
  float mean = (red[0] + red[1] + red[2] + red[3]) * (1.0f / DM);
  float d0 = v.x - mean, d1 = v.y - mean, d2 = v.z - mean, d3 = v.w - mean;
  float s2 = d0*d0 + d1*d1 + d2*d2 + d3*d3;
  #pragma unroll
  for (int o = 32; o; o >>= 1) s2 += __shfl_down(s2, o);
  if (!ln) red[4 + wv] = s2;
  __syncthreads();
  float var = (red[4] + red[5] + red[6] + red[7]) * (1.0f / DM);
  float rs = rsqrtf(var + 1e-5f);
  float4 gg = *(const float4*)(g + tid * 4);
  float4 bv = *(const float4*)(bb + tid * 4);
  float y0 = d0 * rs * gg.x + bv.x;
  float y1 = d1 * rs * gg.y + bv.y;
  float y2 = d2 * rs * gg.z + bv.z;
  float y3 = d3 * rs * gg.w + bv.w;
  if (OUTF32) {
    float4 ov = {y0, y1, y2, y3};
    *(float4*)(of + (size_t)row * DM + tid * 4) = ov;
  } else {
    union { bf16 h[4]; uint2 u; } t;
    t.h[0] = __float2bfloat16(y0); t.h[1] = __float2bfloat16(y1);
    t.h[2] = __float2bfloat16(y2); t.h[3] = __float2bfloat16(y3);
    *(uint2*)(ob + (size_t)row * DM + tid * 4) = t.u;
  }
}

// ---------------- GEMM: C[M,N] = A[M,K] x Bt[N,K]^T (+epilogue) ----------------
// Double-buffered LDS (T3 minimum 2-phase): STAGE(t+1) issued BEFORE compute(t),
// one vmcnt(0)+barrier per K-step -> load latency hides under MFMA+ds_read.
// EPI 0: bf16 out, +bias[col]
// EPI 1: bf16 out, +bias[col], relu
// EPI 2: bf16 out, +bias[row]          (used to produce V^T directly)
// EPI 3: f32   Cf[row,col] += acc + bias[col]   (residual accumulate)
template<int EPI>
__global__ __launch_bounds__(256) void gemm_bt(const bf16* __restrict__ A,
                                               const bf16* __restrict__ Bt,
                                               const float* __restrict__ bias,
                                               bf16* __restrict__ Cb,
                                               float* __restrict__ Cf,
                                               int M, int N, int K) {
  __shared__ bf16 As[2][128 * 32];
  __shared__ bf16 Bs[2][128 * 32];
  int tid = threadIdx.x;
  int wave = tid >> 6, lane = tid & 63;
  int l4 = lane & 15, lhi = lane >> 4;
  int wr = wave >> 1, wc = wave & 1;            // 2x2 waves, 64x64 each
  // XCD-aware bid swizzle (all grids have nwg % 8 == 0)
  int nwg = gridDim.x * gridDim.y;
  int bid = blockIdx.y * gridDim.x + blockIdx.x;
  int cpx = nwg >> 3;
  int swz = (bid & 7) * cpx + (bid >> 3);
  int bx = swz % gridDim.x, by = swz / gridDim.x;
  int brow = by * 128, bcol = bx * 128;
  f32x4 acc[4][4] = {};
  int srow = lane >> 2;                          // 0..15
  int scol = (lane & 3) * 8;                     // bf16 elem offset

  auto stage = [&](int buf, int k0) {
    #pragma unroll
    for (int i = 0; i < 2; ++i) {
      int rb = i * 64 + wave * 16;               // wave-uniform row base
      gl_lds16(A  + (size_t)(brow + rb + srow) * K + k0 + scol, &As[buf][rb * 32]);
      gl_lds16(Bt + (size_t)(bcol + rb + srow) * K + k0 + scol, &Bs[buf][rb * 32]);
    }
  };
  auto compute = [&](int buf) {
    bf16x8 af[4], bfv[4];
    #pragma unroll
    for (int m = 0; m < 4; ++m)
      af[m] = *(const bf16x8*)&As[buf][(wr * 64 + m * 16 + l4) * 32 + lhi * 8];
    #pragma unroll
    for (int n = 0; n < 4; ++n)
      bfv[n] = *(const bf16x8*)&Bs[buf][(wc * 64 + n * 16 + l4) * 32 + lhi * 8];
    #pragma unroll
    for (int m = 0; m < 4; ++m)
      #pragma unroll
      for (int n = 0; n < 4; ++n)
        acc[m][n] = __builtin_amdgcn_mfma_f32_16x16x32_bf16(af[m], bfv[n], acc[m][n], 0, 0, 0);
  };

  stage(0, 0);
  __syncthreads();                 // includes vmcnt(0) drain
  int cur = 0;
  for (int k0 = 32; k0 < K; k0 += 32) {
    stage(cur ^ 1, k0);            // prefetch next tile (overlaps compute)
    compute(cur);
    __syncthreads();               // vmcnt(0): next tile landed; LDS reads of cur done
    cur ^= 1;
  }
  compute(cur);                    // last tile

  #pragma unroll
  for (int m = 0; m < 4; ++m) {
    int row0 = brow + wr * 64 + m * 16 + lhi * 4;
    #pragma unroll
    for (int n = 0; n < 4; ++n) {
      int col = bcol + wc * 64 + n * 16 + l4;
      #pragma unroll
      for (int r = 0; r < 4; ++r) {
        int row = row0 + r;
        float v = acc[m][n][r];
        if (EPI == 0) {
          v += bias[col];
          Cb[(size_t)row * N + col] = __float2bfloat16(v);
        } else if (EPI == 1) {
          v += bias[col];
          v = fmaxf(v, 0.0f);
          Cb[(size_t)row * N + col] = __float2bfloat16(v);
        } else if (EPI == 2) {
          v += bias[row];
          Cb[(size_t)row * N + col] = __float2bfloat16(v);
        } else {
          v += bias[col];
          size_t idx = (size_t)row * N + col;
          Cf[idx] = Cf[idx] + v;
        }
      }
    }
  }
}

// ---------------- fused attention ----------------
// q: [NTOK, qs] bf16 (col offset h*HD); k: [NTOK, ks] bf16; vT: [DM, NTOK] bf16
// out: [NTOK, DM] bf16. grid: (SEQL/64, NB*NH); 4 waves, wave owns 16 q-rows.
template<int CAUSAL>
__global__ __launch_bounds__(256, 2) void attn_kernel(const bf16* __restrict__ qg,
                                                      const bf16* __restrict__ kg,
                                                      const bf16* __restrict__ vtg,
                                                      bf16* __restrict__ og,
                                                      int qs, int ks) {
  __shared__ bf16 P[4][16][520];   // per-wave P rows, padded
  int qblk = blockIdx.x;
  int bh = blockIdx.y;
  int b = bh >> 4, h = bh & 15;
  int wave = threadIdx.x >> 6, lane = threadIdx.x & 63;
  int l4 = lane & 15, lhi = lane >> 4;

  bf16x8 qa[2];
  {
    size_t qrow = (size_t)(b * SEQL + qblk * 64 + wave * 16 + l4);
    #pragma unroll
    for (int kk = 0; kk < 2; ++kk)
      qa[kk] = *(const bf16x8*)&qg[qrow * qs + h * HD + kk * 32 + lhi * 8];
  }
  // QK^T: scores[16 q][512 keys] per wave
  f32x4 acc[32] = {};
  #pragma unroll
  for (int n = 0; n < 32; ++n) {
    #pragma unroll
    for (int kk = 0; kk < 2; ++kk) {
      bf16x8 kf = *(const bf16x8*)&kg[(size_t)(b * SEQL + n * 16 + l4) * ks + h * HD + kk * 32 + lhi * 8];
      acc[n] = __builtin_amdgcn_mfma_f32_16x16x32_bf16(qa[kk], kf, acc[n], 0, 0, 0);
    }
  }
  // softmax (row-wise over 512), C layout: col=n*16+l4, row=lhi*4+r
  int qloc = qblk * 64 + wave * 16 + lhi * 4;
  #pragma unroll
  for (int r = 0; r < 4; ++r) {
    float mx = -3.0e38f;
    #pragma unroll
    for (int n = 0; n < 32; ++n) {
      float sv = acc[n][r] * 0.125f;
      if (CAUSAL && (n * 16 + l4 > qloc + r)) sv = -3.0e38f;
      acc[n][r] = sv;
      mx = fmaxf(mx, sv);
    }
    #pragma unroll
    for (int o = 1; o < 16; o <<= 1) mx = fmaxf(mx, __shfl_xor(mx, o));
    float sum = 0.0f;
    #pragma unroll
    for (int n = 0; n < 32; ++n) {
      float p = __expf(acc[n][r] - mx);
      acc[n][r] = p;
      sum += p;
    }
    #pragma unroll
    for (int o = 1; o < 16; o <<= 1) sum += __shfl_xor(sum, o);
    float rcp = 1.0f / sum;
    #pragma unroll
    for (int n = 0; n < 32; ++n)
      P[wave][lhi * 4 + r][n * 16 + l4] = __float2bfloat16(acc[n][r] * rcp);
  }
  __syncthreads();
  // PV: out[16 q][64 d] per wave; A-frags from P LDS, B-frags from vT global
  f32x4 oacc[4] = {};
  #pragma unroll
  for (int kslot = 0; kslot < 16; ++kslot) {
    bf16x8 pa = *(const bf16x8*)&P[wave][l4][kslot * 32 + lhi * 8];
    #pragma unroll
    for (int n = 0; n < 4; ++n) {
      bf16x8 vf = *(const bf16x8*)&vtg[(size_t)(h * HD + n * 16 + l4) * NTOK + b * SEQL + kslot * 32 + lhi * 8];
      oacc[n] = __builtin_amdgcn_mfma_f32_16x16x32_bf16(pa, vf, oacc[n], 0, 0, 0);
    }
  }
  size_t orow = (size_t)(b * SEQL + qblk * 64 + wave * 16 + lhi * 4);
  #pragma unroll
  for (int n = 0; n < 4; ++n)
    #pragma unroll
    for (int r = 0; r < 4; ++r)
      og[(orow + r) * DM + h * HD + n * 16 + l4] = __float2bfloat16(oacc[n][r]);
}

// ---------------- host ----------------
extern "C" void kernel_launch(void* const* d_in, const int* in_sizes, int n_in,
                              void* d_out, int out_size, void* d_ws, size_t ws_size,
                              hipStream_t stream) {
  (void)in_sizes; (void)n_in; (void)out_size;
  const float* enc   = (const float*)d_in[0];
  const int*   toks  = (const int*)  d_in[1];
  const float* table = (const float*)d_in[4];
  const float* sa_w  = (const float*)d_in[5];
  const float* sa_b  = (const float*)d_in[6];
  const float* ca_w  = (const float*)d_in[7];
  const float* ca_b  = (const float*)d_in[8];
  const float* f1w   = (const float*)d_in[9];
  const float* f1b   = (const float*)d_in[10];
  const float* f2w   = (const float*)d_in[11];
  const float* f2b   = (const float*)d_in[12];
  const float* lng   = (const float*)d_in[13];
  const float* lnbp  = (const float*)d_in[14];
  const float* fg    = (const float*)d_in[15];
  const float* fbp   = (const float*)d_in[16];
  float* outp = (float*)d_out;

  char* base = (char*)d_ws;
  size_t off = 0;
  auto alloc = [&](size_t nbytes) -> char* {
    char* p = base + off;
    off += (nbytes + 255) & ~(size_t)255;
    return p;
  };
  const size_t DDb = (size_t)DM * DM;
  bf16* wt_sa  = (bf16*)alloc((size_t)NL * 4 * DDb * 2);
  bf16* wt_ca  = (bf16*)alloc((size_t)NL * 4 * DDb * 2);
  bf16* wt_f1  = (bf16*)alloc((size_t)NL * FF * DM * 2);
  bf16* wt_f2  = (bf16*)alloc((size_t)NL * FF * DM * 2);
  bf16* encb   = (bf16*)alloc((size_t)NTOK * DM * 2);
  bf16* hbuf   = (bf16*)alloc((size_t)NTOK * DM * 2);
  bf16* qkbuf  = (bf16*)alloc((size_t)NTOK * 2 * DM * 2);  // fused Q|K (stride 2048)
  bf16* vtbuf  = (bf16*)alloc((size_t)NTOK * DM * 2);
  bf16* aobuf  = (bf16*)alloc((size_t)NTOK * DM * 2);
  bf16* kebuf  = (bf16*)alloc((size_t)NTOK * DM * 2);
  bf16* vtebuf = (bf16*)alloc((size_t)NTOK * DM * 2);
  bf16* h1buf  = (bf16*)alloc((size_t)NTOK * FF * 2);
  float* xbuf  = (float*)alloc((size_t)NTOK * DM * 4);
  if (off > ws_size) return;   // workspace too small -> clean failure

  dim3 tb(32, 8);
  transpose_cvt<<<dim3(DM/32, DM/32, NL*4), tb, 0, stream>>>(sa_w, wt_sa, DM, DM);
  transpose_cvt<<<dim3(DM/32, DM/32, NL*4), tb, 0, stream>>>(ca_w, wt_ca, DM, DM);
  transpose_cvt<<<dim3(FF/32, DM/32, NL),   tb, 0, stream>>>(f1w, wt_f1, DM, FF);
  transpose_cvt<<<dim3(DM/32, FF/32, NL),   tb, 0, stream>>>(f2w, wt_f2, FF, DM);
  cvt_bf16<<<(NTOK * DM / 4) / 256, 256, 0, stream>>>(enc, encb);
  embed_pe<<<NTOK, 256, 0, stream>>>(toks, table, xbuf);

  for (int l = 0; l < NL; ++l) {
    const bf16* wsa = wt_sa + (size_t)l * 4 * DDb;
    const bf16* wca = wt_ca + (size_t)l * 4 * DDb;
    const float* bsa = sa_b + (size_t)l * 4 * DM;
    const float* bca = ca_b + (size_t)l * 4 * DM;
    // ---- self-attention (pre-norm) ----
    ln_kernel<0><<<NTOK, 256, 0, stream>>>(xbuf, lng + (l*3+0)*DM, lnbp + (l*3+0)*DM, hbuf, nullptr);
    // fused Q|K projection: Bt rows 0..2047 = [Wq^T; Wk^T], bias contiguous
    gemm_bt<0><<<dim3(2*DM/128, NTOK/128), 256, 0, stream>>>(hbuf, wsa + 0*DDb, bsa + 0*DM, qkbuf, nullptr, NTOK, 2*DM, DM);
    gemm_bt<2><<<dim3(NTOK/128, DM/128), 256, 0, stream>>>(wsa + 2*DDb, hbuf, bsa + 2*DM, vtbuf, nullptr, DM, NTOK, DM);
    attn_kernel<1><<<dim3(SEQL/64, NB*NH), 256, 0, stream>>>(qkbuf, qkbuf + DM, vtbuf, aobuf, 2*DM, 2*DM);
    gemm_bt<3><<<dim3(DM/128, NTOK/128), 256, 0, stream>>>(aobuf, wsa + 3*DDb, bsa + 3*DM, nullptr, xbuf, NTOK, DM, DM);
    // ---- cross-attention (pre-norm) ----
    ln_kernel<0><<<NTOK, 256, 0, stream>>>(xbuf, lng + (l*3+1)*DM, lnbp + (l*3+1)*DM, hbuf, nullptr);
    gemm_bt<0><<<dim3(DM/128, NTOK/128), 256, 0, stream>>>(hbuf, wca + 0*DDb, bca + 0*DM, qkbuf, nullptr, NTOK, DM, DM);
    gemm_bt<0><<<dim3(DM/128, NTOK/128), 256, 0, stream>>>(encb, wca + 1*DDb, bca + 1*DM, kebuf, nullptr, NTOK, DM, DM);
    gemm_bt<2><<<dim3(NTOK/128, DM/128), 256, 0, stream>>>(wca + 2*DDb, encb, bca + 2*DM, vtebuf, nullptr, DM, NTOK, DM);
    attn_kernel<0><<<dim3(SEQL/64, NB*NH), 256, 0, stream>>>(qkbuf, kebuf, vtebuf, aobuf, DM, DM);
    gemm_bt<3><<<dim3(DM/128, NTOK/128), 256, 0, stream>>>(aobuf, wca + 3*DDb, bca + 3*DM, nullptr, xbuf, NTOK, DM, DM);
    // ---- FFN (pre-norm) ----
    ln_kernel<0><<<NTOK, 256, 0, stream>>>(xbuf, lng + (l*3+2)*DM, lnbp + (l*3+2)*DM, hbuf, nullptr);
    gemm_bt<1><<<dim3(FF/128, NTOK/128), 256, 0, stream>>>(hbuf, wt_f1 + (size_t)l*FF*DM, f1b + (size_t)l*FF, h1buf, nullptr, NTOK, FF, DM);
    gemm_bt<3><<<dim3(DM/128, NTOK/128), 256, 0, stream>>>(h1buf, wt_f2 + (size_t)l*FF*DM, f2b + (size_t)l*DM, nullptr, xbuf, NTOK, DM, FF);
  }
  ln_kernel<1><<<NTOK, 256, 0, stream>>>(xbuf, fg, fbp, nullptr, outp);
}

// Round 3
// 3386.337 us; speedup vs baseline: 1.1096x; 1.0368x over previous
//
#include <hip/hip_runtime.h>
#include <hip/hip_bf16.h>

typedef __attribute__((ext_vector_type(8))) short bf16x8;
typedef __attribute__((ext_vector_type(4))) float f32x4;
typedef __hip_bfloat16 bf16;

constexpr int DM   = 1024;
constexpr int NH   = 16;
constexpr int HD   = 64;
constexpr int FF   = 4096;
constexpr int NL   = 6;
constexpr int NB   = 8;
constexpr int SEQL = 512;
constexpr int NTOK = NB * SEQL;   // 4096

// ---------------- async global->LDS (16B) ----------------
__device__ __forceinline__ void gl_lds16(const void* g, void* l) {
  __builtin_amdgcn_global_load_lds(
      (const __attribute__((address_space(1))) unsigned int*)g,
      (__attribute__((address_space(3))) unsigned int*)l, 16, 0, 0);
}

// ---------------- weight transpose + f32->bf16 ----------------
// src: [R][C] f32 (batch z), dst: [C][R] bf16
__global__ __launch_bounds__(256) void transpose_cvt(const float* __restrict__ src,
                                                     bf16* __restrict__ dst,
                                                     int R, int C) {
  __shared__ float tile[32][33];
  size_t mo = (size_t)blockIdx.z * R * C;
  src += mo; dst += mo;
  int c0 = blockIdx.x * 32, r0 = blockIdx.y * 32;
  int tx = threadIdx.x, ty = threadIdx.y;   // 32 x 8
  #pragma unroll
  for (int j = 0; j < 4; ++j)
    tile[ty + 8*j][tx] = src[(size_t)(r0 + ty + 8*j) * C + c0 + tx];
  __syncthreads();
  #pragma unroll
  for (int j = 0; j < 4; ++j)
    dst[(size_t)(c0 + ty + 8*j) * R + r0 + tx] = __float2bfloat16(tile[tx][ty + 8*j]);
}

__global__ __launch_bounds__(256) void cvt_bf16(const float* __restrict__ s,
                                                bf16* __restrict__ d) {
  size_t i = (size_t)blockIdx.x * 256 + threadIdx.x;
  float4 v = ((const float4*)s)[i];
  union { bf16 h[4]; uint2 u; } t;
  t.h[0] = __float2bfloat16(v.x); t.h[1] = __float2bfloat16(v.y);
  t.h[2] = __float2bfloat16(v.z); t.h[3] = __float2bfloat16(v.w);
  *(uint2*)(d + i * 4) = t.u;
}

// ---------------- embedding + positional encoding ----------------
__global__ __launch_bounds__(256) void embed_pe(const int* __restrict__ tok,
                                                const float* __restrict__ table,
                                                float* __restrict__ x) {
  int t = blockIdx.x;               // token index (b*512+s)
  int s = t & (SEQL - 1);
  int tk = tok[t];
  int d = threadIdx.x * 4;
  float4 e = *(const float4*)(table + (size_t)tk * DM + d);
  float o[4] = {e.x, e.y, e.z, e.w};
  const float NEGC = -9.210340371976184f / 1024.0f;   // -ln(10000)/D
  #pragma unroll
  for (int i = 0; i < 4; ++i) {
    int dd = d + i;
    float div = __expf((float)(dd & ~1) * NEGC);
    float arg = (float)s * div;
    float pe = (dd & 1) ? cosf(arg) : sinf(arg);
    o[i] = o[i] * 32.0f + pe;       // sqrt(1024)=32
  }
  float4 ov = {o[0], o[1], o[2], o[3]};
  *(float4*)(x + (size_t)t * DM + d) = ov;
}

// ---------------- layernorm (row=1024), out bf16 or f32 ----------------
template<int OUTF32>
__global__ __launch_bounds__(256) void ln_kernel(const float* __restrict__ x,
                                                 const float* __restrict__ g,
                                                 const float* __restrict__ bb,
                                                 bf16* __restrict__ ob,
                                                 float* __restrict__ of) {
  int row = blockIdx.x;
  int tid = threadIdx.x;
  const float4 v = *(const float4*)(x + (size_t)row * DM + tid * 4);
  float s = v.x + v.y + v.z + v.w;
  #pragma unroll
  for (int o = 32; o; o >>= 1) s += __shfl_down(s, o);
  __shared__ float red[8];
  int wv = tid >> 6, ln = tid & 63;
  if (!ln) red[wv] = s;
  __syncthreads();
  float mean = (red[0] + red[1] + red[2] + red[3]) * (1.0f / DM);
  float d0 = v.x - mean, d1 = v.y - mean, d2 = v.z - mean, d3 = v.w - mean;
  float s2 = d0*d0 + d1*d1 + d2*d2 + d3*d3;
  #pragma unroll
  for (int o = 32; o; o >>= 1) s2 += __shfl_down(s2, o);
  if (!ln) red[4 + wv] = s2;
  __syncthreads();
  float var = (red[4] + red[5] + red[6] + red[7]) * (1.0f / DM);
  float rs = rsqrtf(var + 1e-5f);
  float4 gg = *(const float4*)(g + tid * 4);
  float4 bv = *(const float4*)(bb + tid * 4);
  float y0 = d0 * rs * gg.x + bv.x;
  float y1 = d1 * rs * gg.y + bv.y;
  float y2 = d2 * rs * gg.z + bv.z;
  float y3 = d3 * rs * gg.w + bv.w;
  if (OUTF32) {
    float4 ov = {y0, y1, y2, y3};
    *(float4*)(of + (size_t)row * DM + tid * 4) = ov;
  } else {
    union { bf16 h[4]; uint2 u; } t;
    t.h[0] = __float2bfloat16(y0); t.h[1] = __float2bfloat16(y1);
    t.h[2] = __float2bfloat16(y2); t.h[3] = __float2bfloat16(y3);
    *(uint2*)(ob + (size_t)row * DM + tid * 4) = t.u;
  }
}

// ---------------- GEMM: C[M,N] = A[M,K] x Bt[N,K]^T (+epilogue) ----------------
// T4 deep pipeline: 3-buffer LDS ring, 2-deep prefetch, counted vmcnt(4)
// (4 global_load_lds per wave per stage), raw s_barrier — loads stay in
// flight ACROSS barriers; never drain vmcnt to 0 in the main loop.
// EPI 0: bf16 out, +bias[col]
// EPI 1: bf16 out, +bias[col], relu
// EPI 2: bf16 out, +bias[row]          (used to produce V^T directly)
// EPI 3: f32   Cf[row,col] += acc + bias[col]   (residual accumulate)
template<int EPI>
__global__ __launch_bounds__(256) void gemm_bt(const bf16* __restrict__ A,
                                               const bf16* __restrict__ Bt,
                                               const float* __restrict__ bias,
                                               bf16* __restrict__ Cb,
                                               float* __restrict__ Cf,
                                               int M, int N, int K) {
  __shared__ bf16 As[3][128 * 32];
  __shared__ bf16 Bs[3][128 * 32];
  int tid = threadIdx.x;
  int wave = tid >> 6, lane = tid & 63;
  int l4 = lane & 15, lhi = lane >> 4;
  int wr = wave >> 1, wc = wave & 1;            // 2x2 waves, 64x64 each
  // XCD-aware bid swizzle (all grids have nwg % 8 == 0)
  int nwg = gridDim.x * gridDim.y;
  int bid = blockIdx.y * gridDim.x + blockIdx.x;
  int cpx = nwg >> 3;
  int swz = (bid & 7) * cpx + (bid >> 3);
  int bx = swz % gridDim.x, by = swz / gridDim.x;
  int brow = by * 128, bcol = bx * 128;
  f32x4 acc[4][4] = {};
  int srow = lane >> 2;                          // 0..15
  int scol = (lane & 3) * 8;                     // bf16 elem offset

  auto stage = [&](int buf, int k0) {
    #pragma unroll
    for (int i = 0; i < 2; ++i) {
      int rb = i * 64 + wave * 16;               // wave-uniform row base
      gl_lds16(A  + (size_t)(brow + rb + srow) * K + k0 + scol, &As[buf][rb * 32]);
      gl_lds16(Bt + (size_t)(bcol + rb + srow) * K + k0 + scol, &Bs[buf][rb * 32]);
    }
  };
  auto compute = [&](int buf) {
    bf16x8 af[4], bfv[4];
    #pragma unroll
    for (int m = 0; m < 4; ++m)
      af[m] = *(const bf16x8*)&As[buf][(wr * 64 + m * 16 + l4) * 32 + lhi * 8];
    #pragma unroll
    for (int n = 0; n < 4; ++n)
      bfv[n] = *(const bf16x8*)&Bs[buf][(wc * 64 + n * 16 + l4) * 32 + lhi * 8];
    #pragma unroll
    for (int m = 0; m < 4; ++m)
      #pragma unroll
      for (int n = 0; n < 4; ++n)
        acc[m][n] = __builtin_amdgcn_mfma_f32_16x16x32_bf16(af[m], bfv[n], acc[m][n], 0, 0, 0);
  };

  int T = K >> 5;
  stage(0, 0);
  stage(1, 32);
  for (int t = 0; t < T; ++t) {
    if (t + 1 < T) {
      asm volatile("s_waitcnt vmcnt(4)" ::: "memory");   // oldest tile landed; next stays in flight
    } else {
      asm volatile("s_waitcnt vmcnt(0)" ::: "memory");   // last tile: drain
    }
    __builtin_amdgcn_s_barrier();
    asm volatile("" ::: "memory");
    if (t + 2 < T) stage((t + 2) % 3, (t + 2) * 32);     // safe: buf was consumed at step t-1
    compute(t % 3);
  }

  #pragma unroll
  for (int m = 0; m < 4; ++m) {
    int row0 = brow + wr * 64 + m * 16 + lhi * 4;
    #pragma unroll
    for (int n = 0; n < 4; ++n) {
      int col = bcol + wc * 64 + n * 16 + l4;
      #pragma unroll
      for (int r = 0; r < 4; ++r) {
        int row = row0 + r;
        float v = acc[m][n][r];
        if (EPI == 0) {
          v += bias[col];
          Cb[(size_t)row * N + col] = __float2bfloat16(v);
        } else if (EPI == 1) {
          v += bias[col];
          v = fmaxf(v, 0.0f);
          Cb[(size_t)row * N + col] = __float2bfloat16(v);
        } else if (EPI == 2) {
          v += bias[row];
          Cb[(size_t)row * N + col] = __float2bfloat16(v);
        } else {
          v += bias[col];
          size_t idx = (size_t)row * N + col;
          Cf[idx] = Cf[idx] + v;
        }
      }
    }
  }
}

// ---------------- fused attention ----------------
// q: [NTOK, qs] bf16 (col offset h*HD); k: [NTOK, ks] bf16; vT: [DM, NTOK] bf16
// out: [NTOK, DM] bf16. grid: (SEQL/64, NB*NH); 4 waves, wave owns 16 q-rows.
template<int CAUSAL>
__global__ __launch_bounds__(256, 2) void attn_kernel(const bf16* __restrict__ qg,
                                                      const bf16* __restrict__ kg,
                                                      const bf16* __restrict__ vtg,
                                                      bf16* __restrict__ og,
                                                      int qs, int ks) {
  __shared__ bf16 P[4][16][520];   // per-wave P rows, padded
  int qblk = blockIdx.x;
  int bh = blockIdx.y;
  int b = bh >> 4, h = bh & 15;
  int wave = threadIdx.x >> 6, lane = threadIdx.x & 63;
  int l4 = lane & 15, lhi = lane >> 4;

  bf16x8 qa[2];
  {
    size_t qrow = (size_t)(b * SEQL + qblk * 64 + wave * 16 + l4);
    #pragma unroll
    for (int kk = 0; kk < 2; ++kk)
      qa[kk] = *(const bf16x8*)&qg[qrow * qs + h * HD + kk * 32 + lhi * 8];
  }
  // QK^T: scores[16 q][512 keys] per wave
  f32x4 acc[32] = {};
  #pragma unroll
  for (int n = 0; n < 32; ++n) {
    #pragma unroll
    for (int kk = 0; kk < 2; ++kk) {
      bf16x8 kf = *(const bf16x8*)&kg[(size_t)(b * SEQL + n * 16 + l4) * ks + h * HD + kk * 32 + lhi * 8];
      acc[n] = __builtin_amdgcn_mfma_f32_16x16x32_bf16(qa[kk], kf, acc[n], 0, 0, 0);
    }
  }
  // softmax (row-wise over 512), C layout: col=n*16+l4, row=lhi*4+r
  int qloc = qblk * 64 + wave * 16 + lhi * 4;
  #pragma unroll
  for (int r = 0; r < 4; ++r) {
    float mx = -3.0e38f;
    #pragma unroll
    for (int n = 0; n < 32; ++n) {
      float sv = acc[n][r] * 0.125f;
      if (CAUSAL && (n * 16 + l4 > qloc + r)) sv = -3.0e38f;
      acc[n][r] = sv;
      mx = fmaxf(mx, sv);
    }
    #pragma unroll
    for (int o = 1; o < 16; o <<= 1) mx = fmaxf(mx, __shfl_xor(mx, o));
    float sum = 0.0f;
    #pragma unroll
    for (int n = 0; n < 32; ++n) {
      float p = __expf(acc[n][r] - mx);
      acc[n][r] = p;
      sum += p;
    }
    #pragma unroll
    for (int o = 1; o < 16; o <<= 1) sum += __shfl_xor(sum, o);
    float rcp = 1.0f / sum;
    #pragma unroll
    for (int n = 0; n < 32; ++n)
      P[wave][lhi * 4 + r][n * 16 + l4] = __float2bfloat16(acc[n][r] * rcp);
  }
  __syncthreads();
  // PV: out[16 q][64 d] per wave; A-frags from P LDS, B-frags from vT global
  f32x4 oacc[4] = {};
  #pragma unroll
  for (int kslot = 0; kslot < 16; ++kslot) {
    bf16x8 pa = *(const bf16x8*)&P[wave][l4][kslot * 32 + lhi * 8];
    #pragma unroll
    for (int n = 0; n < 4; ++n) {
      bf16x8 vf = *(const bf16x8*)&vtg[(size_t)(h * HD + n * 16 + l4) * NTOK + b * SEQL + kslot * 32 + lhi * 8];
      oacc[n] = __builtin_amdgcn_mfma_f32_16x16x32_bf16(pa, vf, oacc[n], 0, 0, 0);
    }
  }
  size_t orow = (size_t)(b * SEQL + qblk * 64 + wave * 16 + lhi * 4);
  #pragma unroll
  for (int n = 0; n < 4; ++n)
    #pragma unroll
    for (int r = 0; r < 4; ++r)
      og[(orow + r) * DM + h * HD + n * 16 + l4] = __float2bfloat16(oacc[n][r]);
}

// ---------------- host ----------------
extern "C" void kernel_launch(void* const* d_in, const int* in_sizes, int n_in,
                              void* d_out, int out_size, void* d_ws, size_t ws_size,
                              hipStream_t stream) {
  (void)in_sizes; (void)n_in; (void)out_size;
  const float* enc   = (const float*)d_in[0];
  const int*   toks  = (const int*)  d_in[1];
  const float* table = (const float*)d_in[4];
  const float* sa_w  = (const float*)d_in[5];
  const float* sa_b  = (const float*)d_in[6];
  const float* ca_w  = (const float*)d_in[7];
  const float* ca_b  = (const float*)d_in[8];
  const float* f1w   = (const float*)d_in[9];
  const float* f1b   = (const float*)d_in[10];
  const float* f2w   = (const float*)d_in[11];
  const float* f2b   = (const float*)d_in[12];
  const float* lng   = (const float*)d_in[13];
  const float* lnbp  = (const float*)d_in[14];
  const float* fg    = (const float*)d_in[15];
  const float* fbp   = (const float*)d_in[16];
  float* outp = (float*)d_out;

  char* base = (char*)d_ws;
  size_t off = 0;
  auto alloc = [&](size_t nbytes) -> char* {
    char* p = base + off;
    off += (nbytes + 255) & ~(size_t)255;
    return p;
  };
  const size_t DDb = (size_t)DM * DM;
  bf16* wt_sa  = (bf16*)alloc((size_t)NL * 4 * DDb * 2);
  bf16* wt_ca  = (bf16*)alloc((size_t)NL * 4 * DDb * 2);
  bf16* wt_f1  = (bf16*)alloc((size_t)NL * FF * DM * 2);
  bf16* wt_f2  = (bf16*)alloc((size_t)NL * FF * DM * 2);
  bf16* encb   = (bf16*)alloc((size_t)NTOK * DM * 2);
  bf16* hbuf   = (bf16*)alloc((size_t)NTOK * DM * 2);
  bf16* qkbuf  = (bf16*)alloc((size_t)NTOK * 2 * DM * 2);  // fused Q|K (stride 2048)
  bf16* vtbuf  = (bf16*)alloc((size_t)NTOK * DM * 2);
  bf16* aobuf  = (bf16*)alloc((size_t)NTOK * DM * 2);
  bf16* kebuf  = (bf16*)alloc((size_t)NTOK * DM * 2);
  bf16* vtebuf = (bf16*)alloc((size_t)NTOK * DM * 2);
  bf16* h1buf  = (bf16*)alloc((size_t)NTOK * FF * 2);
  float* xbuf  = (float*)alloc((size_t)NTOK * DM * 4);
  if (off > ws_size) return;   // workspace too small -> clean failure

  dim3 tb(32, 8);
  transpose_cvt<<<dim3(DM/32, DM/32, NL*4), tb, 0, stream>>>(sa_w, wt_sa, DM, DM);
  transpose_cvt<<<dim3(DM/32, DM/32, NL*4), tb, 0, stream>>>(ca_w, wt_ca, DM, DM);
  transpose_cvt<<<dim3(FF/32, DM/32, NL),   tb, 0, stream>>>(f1w, wt_f1, DM, FF);
  transpose_cvt<<<dim3(DM/32, FF/32, NL),   tb, 0, stream>>>(f2w, wt_f2, FF, DM);
  cvt_bf16<<<(NTOK * DM / 4) / 256, 256, 0, stream>>>(enc, encb);
  embed_pe<<<NTOK, 256, 0, stream>>>(toks, table, xbuf);

  for (int l = 0; l < NL; ++l) {
    const bf16* wsa = wt_sa + (size_t)l * 4 * DDb;
    const bf16* wca = wt_ca + (size_t)l * 4 * DDb;
    const float* bsa = sa_b + (size_t)l * 4 * DM;
    const float* bca = ca_b + (size_t)l * 4 * DM;
    // ---- self-attention (pre-norm) ----
    ln_kernel<0><<<NTOK, 256, 0, stream>>>(xbuf, lng + (l*3+0)*DM, lnbp + (l*3+0)*DM, hbuf, nullptr);
    // fused Q|K projection: Bt rows 0..2047 = [Wq^T; Wk^T], bias contiguous
    gemm_bt<0><<<dim3(2*DM/128, NTOK/128), 256, 0, stream>>>(hbuf, wsa + 0*DDb, bsa + 0*DM, qkbuf, nullptr, NTOK, 2*DM, DM);
    gemm_bt<2><<<dim3(NTOK/128, DM/128), 256, 0, stream>>>(wsa + 2*DDb, hbuf, bsa + 2*DM, vtbuf, nullptr, DM, NTOK, DM);
    attn_kernel<1><<<dim3(SEQL/64, NB*NH), 256, 0, stream>>>(qkbuf, qkbuf + DM, vtbuf, aobuf, 2*DM, 2*DM);
    gemm_bt<3><<<dim3(DM/128, NTOK/128), 256, 0, stream>>>(aobuf, wsa + 3*DDb, bsa + 3*DM, nullptr, xbuf, NTOK, DM, DM);
    // ---- cross-attention (pre-norm) ----
    ln_kernel<0><<<NTOK, 256, 0, stream>>>(xbuf, lng + (l*3+1)*DM, lnbp + (l*3+1)*DM, hbuf, nullptr);
    gemm_bt<0><<<dim3(DM/128, NTOK/128), 256, 0, stream>>>(hbuf, wca + 0*DDb, bca + 0*DM, qkbuf, nullptr, NTOK, DM, DM);
    gemm_bt<0><<<dim3(DM/128, NTOK/128), 256, 0, stream>>>(encb, wca + 1*DDb, bca + 1*DM, kebuf, nullptr, NTOK, DM, DM);
    gemm_bt<2><<<dim3(NTOK/128, DM/128), 256, 0, stream>>>(wca + 2*DDb, encb, bca + 2*DM, vtebuf, nullptr, DM, NTOK, DM);
    attn_kernel<0><<<dim3(SEQL/64, NB*NH), 256, 0, stream>>>(qkbuf, kebuf, vtebuf, aobuf, DM, DM);
    gemm_bt<3><<<dim3(DM/128, NTOK/128), 256, 0, stream>>>(aobuf, wca + 3*DDb, bca + 3*DM, nullptr, xbuf, NTOK, DM, DM);
    // ---- FFN (pre-norm) ----
    ln_kernel<0><<<NTOK, 256, 0, stream>>>(xbuf, lng + (l*3+2)*DM, lnbp + (l*3+2)*DM, hbuf, nullptr);
    gemm_bt<1><<<dim3(FF/128, NTOK/128), 256, 0, stream>>>(hbuf, wt_f1 + (size_t)l*FF*DM, f1b + (size_t)l*FF, h1buf, nullptr, NTOK, FF, DM);
    gemm_bt<3><<<dim3(DM/128, NTOK/128), 256, 0, stream>>>(h1buf, wt_f2 + (size_t)l*FF*DM, f2b + (size_t)l*DM, nullptr, xbuf, NTOK, DM, FF);
  }
  ln_kernel<1><<<NTOK, 256, 0, stream>>>(xbuf, fg, fbp, nullptr, outp);
}

// Round 4
// 3118.386 us; speedup vs baseline: 1.2049x; 1.0859x over previous
//
#include <hip/hip_runtime.h>
#include <hip/hip_bf16.h>

typedef __attribute__((ext_vector_type(8))) short bf16x8;
typedef __attribute__((ext_vector_type(4))) float f32x4;
typedef __hip_bfloat16 bf16;

constexpr int DM   = 1024;
constexpr int NH   = 16;
constexpr int HD   = 64;
constexpr int FF   = 4096;
constexpr int NL   = 6;
constexpr int NB   = 8;
constexpr int SEQL = 512;
constexpr int NTOK = NB * SEQL;   // 4096

// ---------------- async global->LDS (16B) ----------------
__device__ __forceinline__ void gl_lds16(const void* g, void* l) {
  __builtin_amdgcn_global_load_lds(
      (const __attribute__((address_space(1))) unsigned int*)g,
      (__attribute__((address_space(3))) unsigned int*)l, 16, 0, 0);
}

// ---------------- weight transpose + f32->bf16 ----------------
__global__ __launch_bounds__(256) void transpose_cvt(const float* __restrict__ src,
                                                     bf16* __restrict__ dst,
                                                     int R, int C) {
  __shared__ float tile[32][33];
  size_t mo = (size_t)blockIdx.z * R * C;
  src += mo; dst += mo;
  int c0 = blockIdx.x * 32, r0 = blockIdx.y * 32;
  int tx = threadIdx.x, ty = threadIdx.y;   // 32 x 8
  #pragma unroll
  for (int j = 0; j < 4; ++j)
    tile[ty + 8*j][tx] = src[(size_t)(r0 + ty + 8*j) * C + c0 + tx];
  __syncthreads();
  #pragma unroll
  for (int j = 0; j < 4; ++j)
    dst[(size_t)(c0 + ty + 8*j) * R + r0 + tx] = __float2bfloat16(tile[tx][ty + 8*j]);
}

__global__ __launch_bounds__(256) void cvt_bf16(const float* __restrict__ s,
                                                bf16* __restrict__ d) {
  size_t i = (size_t)blockIdx.x * 256 + threadIdx.x;
  float4 v = ((const float4*)s)[i];
  union { bf16 h[4]; uint2 u; } t;
  t.h[0] = __float2bfloat16(v.x); t.h[1] = __float2bfloat16(v.y);
  t.h[2] = __float2bfloat16(v.z); t.h[3] = __float2bfloat16(v.w);
  *(uint2*)(d + i * 4) = t.u;
}

// ---------------- embedding + positional encoding ----------------
__global__ __launch_bounds__(256) void embed_pe(const int* __restrict__ tok,
                                                const float* __restrict__ table,
                                                float* __restrict__ x) {
  int t = blockIdx.x;               // token index (b*512+s)
  int s = t & (SEQL - 1);
  int tk = tok[t];
  int d = threadIdx.x * 4;
  float4 e = *(const float4*)(table + (size_t)tk * DM + d);
  float o[4] = {e.x, e.y, e.z, e.w};
  const float NEGC = -9.210340371976184f / 1024.0f;   // -ln(10000)/D
  #pragma unroll
  for (int i = 0; i < 4; ++i) {
    int dd = d + i;
    float div = __expf((float)(dd & ~1) * NEGC);
    float arg = (float)s * div;
    float pe = (dd & 1) ? cosf(arg) : sinf(arg);
    o[i] = o[i] * 32.0f + pe;       // sqrt(1024)=32
  }
  float4 ov = {o[0], o[1], o[2], o[3]};
  *(float4*)(x + (size_t)t * DM + d) = ov;
}

// ---------------- layernorm core ----------------
__device__ __forceinline__ void ln_core(float4 xv, const float* g, const float* bb,
                                        int row, int tid, bf16* ob, float* of, int outf32) {
  float s = xv.x + xv.y + xv.z + xv.w;
  #pragma unroll
  for (int o = 32; o; o >>= 1) s += __shfl_down(s, o);
  __shared__ float red[8];
  int wv = tid >> 6, ln = tid & 63;
  if (!ln) red[wv] = s;
  __syncthreads();
  float mean = (red[0] + red[1] + red[2] + red[3]) * (1.0f / DM);
  float d0 = xv.x - mean, d1 = xv.y - mean, d2 = xv.z - mean, d3 = xv.w - mean;
  float s2 = d0*d0 + d1*d1 + d2*d2 + d3*d3;
  #pragma unroll
  for (int o = 32; o; o >>= 1) s2 += __shfl_down(s2, o);
  if (!ln) red[4 + wv] = s2;
  __syncthreads();
  float var = (red[4] + red[5] + red[6] + red[7]) * (1.0f / DM);
  float rs = rsqrtf(var + 1e-5f);
  float4 gg = *(const float4*)(g + tid * 4);
  float4 bv = *(const float4*)(bb + tid * 4);
  float y0 = d0 * rs * gg.x + bv.x;
  float y1 = d1 * rs * gg.y + bv.y;
  float y2 = d2 * rs * gg.z + bv.z;
  float y3 = d3 * rs * gg.w + bv.w;
  if (outf32) {
    float4 ov = {y0, y1, y2, y3};
    *(float4*)(of + (size_t)row * DM + tid * 4) = ov;
  } else {
    union { bf16 h[4]; uint2 u; } t;
    t.h[0] = __float2bfloat16(y0); t.h[1] = __float2bfloat16(y1);
    t.h[2] = __float2bfloat16(y2); t.h[3] = __float2bfloat16(y3);
    *(uint2*)(ob + (size_t)row * DM + tid * 4) = t.u;
  }
}

template<int OUTF32>
__global__ __launch_bounds__(256) void ln_kernel(const float* __restrict__ x,
                                                 const float* __restrict__ g,
                                                 const float* __restrict__ bb,
                                                 bf16* __restrict__ ob,
                                                 float* __restrict__ of) {
  int row = blockIdx.x, tid = threadIdx.x;
  float4 v = *(const float4*)(x + (size_t)row * DM + tid * 4);
  ln_core(v, g, bb, row, tid, ob, of, OUTF32);
}

// x += p0 + p1 + bias  (split-K reduction), write x back, then LN
template<int OUTF32>
__global__ __launch_bounds__(256) void ln_fused(float* __restrict__ x,
                                                const float* __restrict__ p0,
                                                const float* __restrict__ p1,
                                                const float* __restrict__ bias,
                                                const float* __restrict__ g,
                                                const float* __restrict__ bb,
                                                bf16* __restrict__ ob,
                                                float* __restrict__ of) {
  int row = blockIdx.x, tid = threadIdx.x;
  size_t idx = (size_t)row * DM + tid * 4;
  float4 xv = *(const float4*)(x + idx);
  float4 a0 = *(const float4*)(p0 + idx);
  float4 a1 = *(const float4*)(p1 + idx);
  float4 bv = *(const float4*)(bias + tid * 4);
  xv.x += a0.x + a1.x + bv.x;
  xv.y += a0.y + a1.y + bv.y;
  xv.z += a0.z + a1.z + bv.z;
  xv.w += a0.w + a1.w + bv.w;
  *(float4*)(x + idx) = xv;
  ln_core(xv, g, bb, row, tid, ob, of, OUTF32);
}

// ---------------- GEMM: C[M,N] = A[M,K] x Bt[N,K]^T (+epilogue) ----------------
// 4-buffer LDS ring, 3-deep prefetch, counted vmcnt(8) (T4), raw s_barrier.
// T2 both-sides XOR swizzle: slot ^= row&3 — applied on the GLOBAL source
// address (global_load_lds writes linearly) and on the LDS read address.
// EPI 0: bf16 out, +bias[col]
// EPI 1: bf16 out, +bias[col], relu
// EPI 2: bf16 out, +bias[row]          (produces V^T directly)
// EPI 3: f32   Cf[row,col] += acc + bias[col]   (residual accumulate)
// EPI 4: f32   Cf[z*M*N + row,col] = acc        (split-K=2 partials, grid.z=2)
template<int EPI>
__global__ __launch_bounds__(256) void gemm_bt(const bf16* __restrict__ A,
                                               const bf16* __restrict__ Bt,
                                               const float* __restrict__ bias,
                                               bf16* __restrict__ Cb,
                                               float* __restrict__ Cf,
                                               int M, int N, int K) {
  __shared__ bf16 As[4][128 * 32];
  __shared__ bf16 Bs[4][128 * 32];
  int tid = threadIdx.x;
  int wave = tid >> 6, lane = tid & 63;
  int l4 = lane & 15, lhi = lane >> 4;
  int wr = wave >> 1, wc = wave & 1;            // 2x2 waves, 64x64 each
  // XCD-aware bid swizzle (nwg % 8 == 0 for all our grids)
  int nwg = gridDim.x * gridDim.y;
  int bid = blockIdx.y * gridDim.x + blockIdx.x;
  int cpx = nwg >> 3;
  int swz = (bid & 7) * cpx + (bid >> 3);
  int bx = swz % gridDim.x, by = swz / gridDim.x;
  int brow = by * 128, bcol = bx * 128;
  f32x4 acc[4][4] = {};
  int srow = lane >> 2;                          // 0..15
  int scol = (((lane & 3) ^ (srow & 3)) * 8);    // inverse-swizzled global slot
  int rsw  = (lhi ^ (l4 & 3)) * 8;               // swizzled read slot

  int kbase = 0, Keff = K;
  if (EPI == 4) { Keff = K >> 1; kbase = blockIdx.z * Keff; }
  int T = Keff >> 5;

  auto stage = [&](int buf, int t) {
    int k0 = kbase + t * 32;
    #pragma unroll
    for (int i = 0; i < 2; ++i) {
      int rb = i * 64 + wave * 16;               // wave-uniform row base
      gl_lds16(A  + (size_t)(brow + rb + srow) * K + k0 + scol, &As[buf][rb * 32]);
      gl_lds16(Bt + (size_t)(bcol + rb + srow) * K + k0 + scol, &Bs[buf][rb * 32]);
    }
  };
  auto compute = [&](int buf) {
    bf16x8 af[4], bfv[4];
    #pragma unroll
    for (int m = 0; m < 4; ++m)
      af[m] = *(const bf16x8*)&As[buf][(wr * 64 + m * 16 + l4) * 32 + rsw];
    #pragma unroll
    for (int n = 0; n < 4; ++n)
      bfv[n] = *(const bf16x8*)&Bs[buf][(wc * 64 + n * 16 + l4) * 32 + rsw];
    #pragma unroll
    for (int m = 0; m < 4; ++m)
      #pragma unroll
      for (int n = 0; n < 4; ++n)
        acc[m][n] = __builtin_amdgcn_mfma_f32_16x16x32_bf16(af[m], bfv[n], acc[m][n], 0, 0, 0);
  };

  stage(0, 0);
  stage(1, 1);
  stage(2, 2);
  for (int t = 0; t < T; ++t) {
    if (t <= T - 3)      asm volatile("s_waitcnt vmcnt(8)" ::: "memory");
    else if (t == T - 2) asm volatile("s_waitcnt vmcnt(4)" ::: "memory");
    else                 asm volatile("s_waitcnt vmcnt(0)" ::: "memory");
    __builtin_amdgcn_s_barrier();
    asm volatile("" ::: "memory");
    if (t + 3 < T) stage((t + 3) & 3, t + 3);    // buf consumed at step t-1
    compute(t & 3);
  }

  #pragma unroll
  for (int m = 0; m < 4; ++m) {
    int row0 = brow + wr * 64 + m * 16 + lhi * 4;
    #pragma unroll
    for (int n = 0; n < 4; ++n) {
      int col = bcol + wc * 64 + n * 16 + l4;
      #pragma unroll
      for (int r = 0; r < 4; ++r) {
        int row = row0 + r;
        float v = acc[m][n][r];
        if (EPI == 0) {
          v += bias[col];
          Cb[(size_t)row * N + col] = __float2bfloat16(v);
        } else if (EPI == 1) {
          v += bias[col];
          v = fmaxf(v, 0.0f);
          Cb[(size_t)row * N + col] = __float2bfloat16(v);
        } else if (EPI == 2) {
          v += bias[row];
          Cb[(size_t)row * N + col] = __float2bfloat16(v);
        } else if (EPI == 3) {
          v += bias[col];
          size_t idx = (size_t)row * N + col;
          Cf[idx] = Cf[idx] + v;
        } else {
          Cf[(size_t)blockIdx.z * ((size_t)M * N) + (size_t)row * N + col] = v;
        }
      }
    }
  }
}

// ---------------- fused attention ----------------
template<int CAUSAL>
__global__ __launch_bounds__(256, 2) void attn_kernel(const bf16* __restrict__ qg,
                                                      const bf16* __restrict__ kg,
                                                      const bf16* __restrict__ vtg,
                                                      bf16* __restrict__ og,
                                                      int qs, int ks) {
  __shared__ bf16 P[4][16][520];   // per-wave P rows, padded
  int qblk = blockIdx.x;
  int bh = blockIdx.y;
  int b = bh >> 4, h = bh & 15;
  int wave = threadIdx.x >> 6, lane = threadIdx.x & 63;
  int l4 = lane & 15, lhi = lane >> 4;

  bf16x8 qa[2];
  {
    size_t qrow = (size_t)(b * SEQL + qblk * 64 + wave * 16 + l4);
    #pragma unroll
    for (int kk = 0; kk < 2; ++kk)
      qa[kk] = *(const bf16x8*)&qg[qrow * qs + h * HD + kk * 32 + lhi * 8];
  }
  f32x4 acc[32] = {};
  #pragma unroll
  for (int n = 0; n < 32; ++n) {
    #pragma unroll
    for (int kk = 0; kk < 2; ++kk) {
      bf16x8 kf = *(const bf16x8*)&kg[(size_t)(b * SEQL + n * 16 + l4) * ks + h * HD + kk * 32 + lhi * 8];
      acc[n] = __builtin_amdgcn_mfma_f32_16x16x32_bf16(qa[kk], kf, acc[n], 0, 0, 0);
    }
  }
  int qloc = qblk * 64 + wave * 16 + lhi * 4;
  #pragma unroll
  for (int r = 0; r < 4; ++r) {
    float mx = -3.0e38f;
    #pragma unroll
    for (int n = 0; n < 32; ++n) {
      float sv = acc[n][r] * 0.125f;
      if (CAUSAL && (n * 16 + l4 > qloc + r)) sv = -3.0e38f;
      acc[n][r] = sv;
      mx = fmaxf(mx, sv);
    }
    #pragma unroll
    for (int o = 1; o < 16; o <<= 1) mx = fmaxf(mx, __shfl_xor(mx, o));
    float sum = 0.0f;
    #pragma unroll
    for (int n = 0; n < 32; ++n) {
      float p = __expf(acc[n][r] - mx);
      acc[n][r] = p;
      sum += p;
    }
    #pragma unroll
    for (int o = 1; o < 16; o <<= 1) sum += __shfl_xor(sum, o);
    float rcp = 1.0f / sum;
    #pragma unroll
    for (int n = 0; n < 32; ++n)
      P[wave][lhi * 4 + r][n * 16 + l4] = __float2bfloat16(acc[n][r] * rcp);
  }
  __syncthreads();
  f32x4 oacc[4] = {};
  #pragma unroll
  for (int kslot = 0; kslot < 16; ++kslot) {
    bf16x8 pa = *(const bf16x8*)&P[wave][l4][kslot * 32 + lhi * 8];
    #pragma unroll
    for (int n = 0; n < 4; ++n) {
      bf16x8 vf = *(const bf16x8*)&vtg[(size_t)(h * HD + n * 16 + l4) * NTOK + b * SEQL + kslot * 32 + lhi * 8];
      oacc[n] = __builtin_amdgcn_mfma_f32_16x16x32_bf16(pa, vf, oacc[n], 0, 0, 0);
    }
  }
  size_t orow = (size_t)(b * SEQL + qblk * 64 + wave * 16 + lhi * 4);
  #pragma unroll
  for (int n = 0; n < 4; ++n)
    #pragma unroll
    for (int r = 0; r < 4; ++r)
      og[(orow + r) * DM + h * HD + n * 16 + l4] = __float2bfloat16(oacc[n][r]);
}

// ---------------- host ----------------
extern "C" void kernel_launch(void* const* d_in, const int* in_sizes, int n_in,
                              void* d_out, int out_size, void* d_ws, size_t ws_size,
                              hipStream_t stream) {
  (void)in_sizes; (void)n_in; (void)out_size;
  const float* enc   = (const float*)d_in[0];
  const int*   toks  = (const int*)  d_in[1];
  const float* table = (const float*)d_in[4];
  const float* sa_w  = (const float*)d_in[5];
  const float* sa_b  = (const float*)d_in[6];
  const float* ca_w  = (const float*)d_in[7];
  const float* ca_b  = (const float*)d_in[8];
  const float* f1w   = (const float*)d_in[9];
  const float* f1b   = (const float*)d_in[10];
  const float* f2w   = (const float*)d_in[11];
  const float* f2b   = (const float*)d_in[12];
  const float* lng   = (const float*)d_in[13];
  const float* lnbp  = (const float*)d_in[14];
  const float* fg    = (const float*)d_in[15];
  const float* fbp   = (const float*)d_in[16];
  float* outp = (float*)d_out;

  char* base = (char*)d_ws;
  size_t off = 0;
  auto alloc = [&](size_t nbytes) -> char* {
    char* p = base + off;
    off += (nbytes + 255) & ~(size_t)255;
    return p;
  };
  const size_t DDb = (size_t)DM * DM;
  bf16* wt_sa  = (bf16*)alloc((size_t)NL * 4 * DDb * 2);
  bf16* wt_ca  = (bf16*)alloc((size_t)NL * 4 * DDb * 2);
  bf16* wt_f1  = (bf16*)alloc((size_t)NL * FF * DM * 2);
  bf16* wt_f2  = (bf16*)alloc((size_t)NL * FF * DM * 2);
  bf16* encb   = (bf16*)alloc((size_t)NTOK * DM * 2);
  bf16* hbuf   = (bf16*)alloc((size_t)NTOK * DM * 2);
  bf16* qkbuf  = (bf16*)alloc((size_t)NTOK * 2 * DM * 2);  // fused Q|K (stride 2048)
  bf16* vtbuf  = (bf16*)alloc((size_t)NTOK * DM * 2);
  bf16* aobuf  = (bf16*)alloc((size_t)NTOK * DM * 2);
  bf16* kebuf  = (bf16*)alloc((size_t)NTOK * DM * 2);
  bf16* vtebuf = (bf16*)alloc((size_t)NTOK * DM * 2);
  bf16* h1buf  = (bf16*)alloc((size_t)NTOK * FF * 2);
  float* xbuf  = (float*)alloc((size_t)NTOK * DM * 4);
  if (off > ws_size) return;   // workspace too small -> clean failure
  // split-K partials alias dead self-attn buffers during FFN2:
  // qkbuf(16MB)+vtbuf(8MB)+aobuf(8MB) = 32MB contiguous = 2 x [NTOK x DM] f32
  float* pbuf = (float*)qkbuf;

  dim3 tb(32, 8);
  transpose_cvt<<<dim3(DM/32, DM/32, NL*4), tb, 0, stream>>>(sa_w, wt_sa, DM, DM);
  transpose_cvt<<<dim3(DM/32, DM/32, NL*4), tb, 0, stream>>>(ca_w, wt_ca, DM, DM);
  transpose_cvt<<<dim3(FF/32, DM/32, NL),   tb, 0, stream>>>(f1w, wt_f1, DM, FF);
  transpose_cvt<<<dim3(DM/32, FF/32, NL),   tb, 0, stream>>>(f2w, wt_f2, FF, DM);
  cvt_bf16<<<(NTOK * DM / 4) / 256, 256, 0, stream>>>(enc, encb);
  embed_pe<<<NTOK, 256, 0, stream>>>(toks, table, xbuf);

  // layer-0 pre-norm (subsequent ln0's are fused into the previous FFN2 reduce)
  ln_kernel<0><<<NTOK, 256, 0, stream>>>(xbuf, lng + 0*DM, lnbp + 0*DM, hbuf, nullptr);

  for (int l = 0; l < NL; ++l) {
    const bf16* wsa = wt_sa + (size_t)l * 4 * DDb;
    const bf16* wca = wt_ca + (size_t)l * 4 * DDb;
    const float* bsa = sa_b + (size_t)l * 4 * DM;
    const float* bca = ca_b + (size_t)l * 4 * DM;
    // ---- self-attention (pre-norm output already in hbuf) ----
    gemm_bt<0><<<dim3(2*DM/128, NTOK/128), 256, 0, stream>>>(hbuf, wsa + 0*DDb, bsa + 0*DM, qkbuf, nullptr, NTOK, 2*DM, DM);
    gemm_bt<2><<<dim3(NTOK/128, DM/128), 256, 0, stream>>>(wsa + 2*DDb, hbuf, bsa + 2*DM, vtbuf, nullptr, DM, NTOK, DM);
    attn_kernel<1><<<dim3(SEQL/64, NB*NH), 256, 0, stream>>>(qkbuf, qkbuf + DM, vtbuf, aobuf, 2*DM, 2*DM);
    gemm_bt<3><<<dim3(DM/128, NTOK/128), 256, 0, stream>>>(aobuf, wsa + 3*DDb, bsa + 3*DM, nullptr, xbuf, NTOK, DM, DM);
    // ---- cross-attention (pre-norm) ----
    ln_kernel<0><<<NTOK, 256, 0, stream>>>(xbuf, lng + (l*3+1)*DM, lnbp + (l*3+1)*DM, hbuf, nullptr);
    gemm_bt<0><<<dim3(DM/128, NTOK/128), 256, 0, stream>>>(hbuf, wca + 0*DDb, bca + 0*DM, qkbuf, nullptr, NTOK, DM, DM);
    gemm_bt<0><<<dim3(DM/128, NTOK/128), 256, 0, stream>>>(encb, wca + 1*DDb, bca + 1*DM, kebuf, nullptr, NTOK, DM, DM);
    gemm_bt<2><<<dim3(NTOK/128, DM/128), 256, 0, stream>>>(wca + 2*DDb, encb, bca + 2*DM, vtebuf, nullptr, DM, NTOK, DM);
    attn_kernel<0><<<dim3(SEQL/64, NB*NH), 256, 0, stream>>>(qkbuf, kebuf, vtebuf, aobuf, DM, DM);
    gemm_bt<3><<<dim3(DM/128, NTOK/128), 256, 0, stream>>>(aobuf, wca + 3*DDb, bca + 3*DM, nullptr, xbuf, NTOK, DM, DM);
    // ---- FFN (pre-norm) ----
    ln_kernel<0><<<NTOK, 256, 0, stream>>>(xbuf, lng + (l*3+2)*DM, lnbp + (l*3+2)*DM, hbuf, nullptr);
    gemm_bt<1><<<dim3(FF/128, NTOK/128), 256, 0, stream>>>(hbuf, wt_f1 + (size_t)l*FF*DM, f1b + (size_t)l*FF, h1buf, nullptr, NTOK, FF, DM);
    // FFN2 split-K=2 -> partials; reduce fused into next LN
    gemm_bt<4><<<dim3(DM/128, NTOK/128, 2), 256, 0, stream>>>(h1buf, wt_f2 + (size_t)l*FF*DM, nullptr, nullptr, pbuf, NTOK, DM, FF);
    if (l < NL - 1)
      ln_fused<0><<<NTOK, 256, 0, stream>>>(xbuf, pbuf, pbuf + (size_t)NTOK*DM, f2b + (size_t)l*DM,
                                            lng + ((l+1)*3+0)*DM, lnbp + ((l+1)*3+0)*DM, hbuf, nullptr);
    else
      ln_fused<1><<<NTOK, 256, 0, stream>>>(xbuf, pbuf, pbuf + (size_t)NTOK*DM, f2b + (size_t)l*DM,
                                            fg, fbp, nullptr, outp);
  }
}

// Round 5
// 2791.349 us; speedup vs baseline: 1.3461x; 1.1172x over previous
//
#include <hip/hip_runtime.h>
#include <hip/hip_bf16.h>

typedef __attribute__((ext_vector_type(8))) short bf16x8;
typedef __attribute__((ext_vector_type(4))) float f32x4;
typedef __hip_bfloat16 bf16;

constexpr int DM   = 1024;
constexpr int NH   = 16;
constexpr int HD   = 64;
constexpr int FF   = 4096;
constexpr int NL   = 6;
constexpr int NB_  = 8;
constexpr int SEQL = 512;
constexpr int NTOK = NB_ * SEQL;   // 4096

// ---------------- async global->LDS (16B) ----------------
__device__ __forceinline__ void gl_lds16(const void* g, void* l) {
  __builtin_amdgcn_global_load_lds(
      (const __attribute__((address_space(1))) unsigned int*)g,
      (__attribute__((address_space(3))) unsigned int*)l, 16, 0, 0);
}

// ---------------- weight transpose + f32->bf16 ----------------
__global__ __launch_bounds__(256) void transpose_cvt(const float* __restrict__ src,
                                                     bf16* __restrict__ dst,
                                                     int R, int C) {
  __shared__ float tile[32][33];
  size_t mo = (size_t)blockIdx.z * R * C;
  src += mo; dst += mo;
  int c0 = blockIdx.x * 32, r0 = blockIdx.y * 32;
  int tx = threadIdx.x, ty = threadIdx.y;   // 32 x 8
  #pragma unroll
  for (int j = 0; j < 4; ++j)
    tile[ty + 8*j][tx] = src[(size_t)(r0 + ty + 8*j) * C + c0 + tx];
  __syncthreads();
  #pragma unroll
  for (int j = 0; j < 4; ++j)
    dst[(size_t)(c0 + ty + 8*j) * R + r0 + tx] = __float2bfloat16(tile[tx][ty + 8*j]);
}

__global__ __launch_bounds__(256) void cvt_bf16(const float* __restrict__ s,
                                                bf16* __restrict__ d) {
  size_t i = (size_t)blockIdx.x * 256 + threadIdx.x;
  float4 v = ((const float4*)s)[i];
  union { bf16 h[4]; uint2 u; } t;
  t.h[0] = __float2bfloat16(v.x); t.h[1] = __float2bfloat16(v.y);
  t.h[2] = __float2bfloat16(v.z); t.h[3] = __float2bfloat16(v.w);
  *(uint2*)(d + i * 4) = t.u;
}

// ---------------- embedding + positional encoding ----------------
__global__ __launch_bounds__(256) void embed_pe(const int* __restrict__ tok,
                                                const float* __restrict__ table,
                                                float* __restrict__ x) {
  int t = blockIdx.x;
  int s = t & (SEQL - 1);
  int tk = tok[t];
  int d = threadIdx.x * 4;
  float4 e = *(const float4*)(table + (size_t)tk * DM + d);
  float o[4] = {e.x, e.y, e.z, e.w};
  const float NEGC = -9.210340371976184f / 1024.0f;   // -ln(10000)/D
  #pragma unroll
  for (int i = 0; i < 4; ++i) {
    int dd = d + i;
    float div = __expf((float)(dd & ~1) * NEGC);
    float arg = (float)s * div;
    float pe = (dd & 1) ? cosf(arg) : sinf(arg);
    o[i] = o[i] * 32.0f + pe;       // sqrt(1024)=32
  }
  float4 ov = {o[0], o[1], o[2], o[3]};
  *(float4*)(x + (size_t)t * DM + d) = ov;
}

// ---------------- layernorm core ----------------
__device__ __forceinline__ void ln_core(float4 xv, const float* g, const float* bb,
                                        int row, int tid, bf16* ob, float* of, int outf32) {
  float s = xv.x + xv.y + xv.z + xv.w;
  #pragma unroll
  for (int o = 32; o; o >>= 1) s += __shfl_down(s, o);
  __shared__ float red[8];
  int wv = tid >> 6, ln = tid & 63;
  if (!ln) red[wv] = s;
  __syncthreads();
  float mean = (red[0] + red[1] + red[2] + red[3]) * (1.0f / DM);
  float d0 = xv.x - mean, d1 = xv.y - mean, d2 = xv.z - mean, d3 = xv.w - mean;
  float s2 = d0*d0 + d1*d1 + d2*d2 + d3*d3;
  #pragma unroll
  for (int o = 32; o; o >>= 1) s2 += __shfl_down(s2, o);
  if (!ln) red[4 + wv] = s2;
  __syncthreads();
  float var = (red[4] + red[5] + red[6] + red[7]) * (1.0f / DM);
  float rs = rsqrtf(var + 1e-5f);
  float4 gg = *(const float4*)(g + tid * 4);
  float4 bv = *(const float4*)(bb + tid * 4);
  float y0 = d0 * rs * gg.x + bv.x;
  float y1 = d1 * rs * gg.y + bv.y;
  float y2 = d2 * rs * gg.z + bv.z;
  float y3 = d3 * rs * gg.w + bv.w;
  if (outf32) {
    float4 ov = {y0, y1, y2, y3};
    *(float4*)(of + (size_t)row * DM + tid * 4) = ov;
  } else {
    union { bf16 h[4]; uint2 u; } t;
    t.h[0] = __float2bfloat16(y0); t.h[1] = __float2bfloat16(y1);
    t.h[2] = __float2bfloat16(y2); t.h[3] = __float2bfloat16(y3);
    *(uint2*)(ob + (size_t)row * DM + tid * 4) = t.u;
  }
}

template<int OUTF32>
__global__ __launch_bounds__(256) void ln_kernel(const float* __restrict__ x,
                                                 const float* __restrict__ g,
                                                 const float* __restrict__ bb,
                                                 bf16* __restrict__ ob,
                                                 float* __restrict__ of) {
  int row = blockIdx.x, tid = threadIdx.x;
  float4 v = *(const float4*)(x + (size_t)row * DM + tid * 4);
  ln_core(v, g, bb, row, tid, ob, of, OUTF32);
}

// x += p0 + p1 + bias  (split-K reduction), write x back, then LN
template<int OUTF32>
__global__ __launch_bounds__(256) void ln_fused(float* __restrict__ x,
                                                const float* __restrict__ p0,
                                                const float* __restrict__ p1,
                                                const float* __restrict__ bias,
                                                const float* __restrict__ g,
                                                const float* __restrict__ bb,
                                                bf16* __restrict__ ob,
                                                float* __restrict__ of) {
  int row = blockIdx.x, tid = threadIdx.x;
  size_t idx = (size_t)row * DM + tid * 4;
  float4 xv = *(const float4*)(x + idx);
  float4 a0 = *(const float4*)(p0 + idx);
  float4 a1 = *(const float4*)(p1 + idx);
  float4 bv = *(const float4*)(bias + tid * 4);
  xv.x += a0.x + a1.x + bv.x;
  xv.y += a0.y + a1.y + bv.y;
  xv.z += a0.z + a1.z + bv.z;
  xv.w += a0.w + a1.w + bv.w;
  *(float4*)(x + idx) = xv;
  ln_core(xv, g, bb, row, tid, ob, of, OUTF32);
}

// ---------------- GEMM: C[M,N] = A[M,K] x Bt[N,K]^T (+epilogue) ----------------
// BM=128 fixed, BN in {64,128}. 3-buffer LDS ring, 2-deep prefetch, counted
// vmcnt(L) (L = loads/wave/stage = 2 + BN/64), raw s_barrier (T4).
// EPI 0: bf16 out, +bias[col]
// EPI 1: bf16 out, +bias[col], relu
// EPI 2: bf16 out, +bias[row]                      (produces V^T directly)
// EPI 3: f32 Cf[row,col] += acc + bias[col]        (residual accumulate)
// EPI 4: f32 Cf[z*M*N + row,col] = acc             (split-K=2 partials)
// EPI 5: bf16 out; B-rows/bias remapped into [L][4][1024] slot 1 (K_enc all-layers)
// EPI 6: bf16 out; A-rows/row-bias remapped slot 2 (V_enc^T all-layers)
template<int EPI, int BN>
__global__ __launch_bounds__(256) void gemm_bt(const bf16* __restrict__ A,
                                               const bf16* __restrict__ Bt,
                                               const float* __restrict__ bias,
                                               bf16* __restrict__ Cb,
                                               float* __restrict__ Cf,
                                               int M, int N, int K) {
  constexpr int NFR = BN / 32;         // col frags per wave
  constexpr int BCH = BN / 64;         // B chunks per wave per stage
  __shared__ bf16 As[3][128 * 32];
  __shared__ bf16 Bs[3][BN * 32];
  int tid = threadIdx.x;
  int wave = tid >> 6, lane = tid & 63;
  int l4 = lane & 15, lhi = lane >> 4;
  int wr = wave >> 1, wc = wave & 1;            // 2x2 waves
  // XCD-aware bid swizzle (nwg % 8 == 0 for all our grids)
  int nwg = gridDim.x * gridDim.y;
  int bid = blockIdx.y * gridDim.x + blockIdx.x;
  int cpx = nwg >> 3;
  int swz = (bid & 7) * cpx + (bid >> 3);
  int bx = swz % gridDim.x, by = swz / gridDim.x;
  int brow = by * 128, bcol = bx * BN;
  f32x4 acc[4][NFR] = {};
  int srow = lane >> 2;                          // 0..15
  int scol = (lane & 3) * 8;

  int kbase = 0, Keff = K;
  if (EPI == 4) { Keff = K >> 1; kbase = blockIdx.z * Keff; }
  int T = Keff >> 5;

  auto stage = [&](int buf, int t) {
    int k0 = kbase + t * 32;
    #pragma unroll
    for (int i = 0; i < 2; ++i) {
      int rr = brow + i * 64 + wave * 16;
      if (EPI == 6) rr = ((rr >> 10) << 12) + 2048 + (rr & 1023);   // Wv slot
      gl_lds16(A + (size_t)(rr + srow) * K + k0 + scol, &As[buf][(i * 64 + wave * 16) * 32]);
    }
    #pragma unroll
    for (int i = 0; i < BCH; ++i) {
      int rr = bcol + i * 64 + wave * 16;
      if (EPI == 5) rr = ((rr >> 10) << 12) + 1024 + (rr & 1023);   // Wk slot
      gl_lds16(Bt + (size_t)(rr + srow) * K + k0 + scol, &Bs[buf][(i * 64 + wave * 16) * 32]);
    }
  };
  auto compute = [&](int buf) {
    bf16x8 af[4], bfv[NFR];
    #pragma unroll
    for (int m = 0; m < 4; ++m)
      af[m] = *(const bf16x8*)&As[buf][(wr * 64 + m * 16 + l4) * 32 + lhi * 8];
    #pragma unroll
    for (int n = 0; n < NFR; ++n)
      bfv[n] = *(const bf16x8*)&Bs[buf][(wc * (BN / 2) + n * 16 + l4) * 32 + lhi * 8];
    #pragma unroll
    for (int m = 0; m < 4; ++m)
      #pragma unroll
      for (int n = 0; n < NFR; ++n)
        acc[m][n] = __builtin_amdgcn_mfma_f32_16x16x32_bf16(af[m], bfv[n], acc[m][n], 0, 0, 0);
  };

  stage(0, 0);
  stage(1, 1);
  for (int t = 0; t < T; ++t) {
    if (t < T - 1) {
      if constexpr (BN == 128) asm volatile("s_waitcnt vmcnt(4)" ::: "memory");
      else                     asm volatile("s_waitcnt vmcnt(3)" ::: "memory");
    } else {
      asm volatile("s_waitcnt vmcnt(0)" ::: "memory");
    }
    __builtin_amdgcn_s_barrier();
    asm volatile("" ::: "memory");
    if (t + 2 < T) stage((t + 2) % 3, t + 2);   // buf consumed at compute(t-1)
    compute(t % 3);
  }

  #pragma unroll
  for (int m = 0; m < 4; ++m) {
    int row0 = brow + wr * 64 + m * 16 + lhi * 4;
    #pragma unroll
    for (int n = 0; n < NFR; ++n) {
      int col = bcol + wc * (BN / 2) + n * 16 + l4;
      #pragma unroll
      for (int r = 0; r < 4; ++r) {
        int row = row0 + r;
        float v = acc[m][n][r];
        if (EPI == 0) {
          v += bias[col];
          Cb[(size_t)row * N + col] = __float2bfloat16(v);
        } else if (EPI == 1) {
          v += bias[col];
          v = fmaxf(v, 0.0f);
          Cb[(size_t)row * N + col] = __float2bfloat16(v);
        } else if (EPI == 2) {
          v += bias[row];
          Cb[(size_t)row * N + col] = __float2bfloat16(v);
        } else if (EPI == 3) {
          v += bias[col];
          size_t idx = (size_t)row * N + col;
          Cf[idx] = Cf[idx] + v;
        } else if (EPI == 4) {
          Cf[(size_t)blockIdx.z * ((size_t)M * N) + (size_t)row * N + col] = v;
        } else if (EPI == 5) {
          v += bias[((col >> 10) << 12) + 1024 + (col & 1023)];
          Cb[(size_t)row * N + col] = __float2bfloat16(v);
        } else {
          v += bias[((row >> 10) << 12) + 2048 + (row & 1023)];
          Cb[(size_t)row * N + col] = __float2bfloat16(v);
        }
      }
    }
  }
}

// ---------------- fused attention ----------------
template<int CAUSAL>
__global__ __launch_bounds__(256, 2) void attn_kernel(const bf16* __restrict__ qg,
                                                      const bf16* __restrict__ kg,
                                                      const bf16* __restrict__ vtg,
                                                      bf16* __restrict__ og,
                                                      int qs, int ks) {
  __shared__ bf16 P[4][16][520];   // per-wave P rows, padded
  int qblk = blockIdx.x;
  int bh = blockIdx.y;
  int b = bh >> 4, h = bh & 15;
  int wave = threadIdx.x >> 6, lane = threadIdx.x & 63;
  int l4 = lane & 15, lhi = lane >> 4;

  bf16x8 qa[2];
  {
    size_t qrow = (size_t)(b * SEQL + qblk * 64 + wave * 16 + l4);
    #pragma unroll
    for (int kk = 0; kk < 2; ++kk)
      qa[kk] = *(const bf16x8*)&qg[qrow * qs + h * HD + kk * 32 + lhi * 8];
  }
  f32x4 acc[32] = {};
  #pragma unroll
  for (int n = 0; n < 32; ++n) {
    #pragma unroll
    for (int kk = 0; kk < 2; ++kk) {
      bf16x8 kf = *(const bf16x8*)&kg[(size_t)(b * SEQL + n * 16 + l4) * ks + h * HD + kk * 32 + lhi * 8];
      acc[n] = __builtin_amdgcn_mfma_f32_16x16x32_bf16(qa[kk], kf, acc[n], 0, 0, 0);
    }
  }
  int qloc = qblk * 64 + wave * 16 + lhi * 4;
  #pragma unroll
  for (int r = 0; r < 4; ++r) {
    float mx = -3.0e38f;
    #pragma unroll
    for (int n = 0; n < 32; ++n) {
      float sv = acc[n][r] * 0.125f;
      if (CAUSAL && (n * 16 + l4 > qloc + r)) sv = -3.0e38f;
      acc[n][r] = sv;
      mx = fmaxf(mx, sv);
    }
    #pragma unroll
    for (int o = 1; o < 16; o <<= 1) mx = fmaxf(mx, __shfl_xor(mx, o));
    float sum = 0.0f;
    #pragma unroll
    for (int n = 0; n < 32; ++n) {
      float p = __expf(acc[n][r] - mx);
      acc[n][r] = p;
      sum += p;
    }
    #pragma unroll
    for (int o = 1; o < 16; o <<= 1) sum += __shfl_xor(sum, o);
    float rcp = 1.0f / sum;
    #pragma unroll
    for (int n = 0; n < 32; ++n)
      P[wave][lhi * 4 + r][n * 16 + l4] = __float2bfloat16(acc[n][r] * rcp);
  }
  __syncthreads();
  f32x4 oacc[4] = {};
  #pragma unroll
  for (int kslot = 0; kslot < 16; ++kslot) {
    bf16x8 pa = *(const bf16x8*)&P[wave][l4][kslot * 32 + lhi * 8];
    #pragma unroll
    for (int n = 0; n < 4; ++n) {
      bf16x8 vf = *(const bf16x8*)&vtg[(size_t)(h * HD + n * 16 + l4) * NTOK + b * SEQL + kslot * 32 + lhi * 8];
      oacc[n] = __builtin_amdgcn_mfma_f32_16x16x32_bf16(pa, vf, oacc[n], 0, 0, 0);
    }
  }
  size_t orow = (size_t)(b * SEQL + qblk * 64 + wave * 16 + lhi * 4);
  #pragma unroll
  for (int n = 0; n < 4; ++n)
    #pragma unroll
    for (int r = 0; r < 4; ++r)
      og[(orow + r) * DM + h * HD + n * 16 + l4] = __float2bfloat16(oacc[n][r]);
}

// ---------------- host ----------------
extern "C" void kernel_launch(void* const* d_in, const int* in_sizes, int n_in,
                              void* d_out, int out_size, void* d_ws, size_t ws_size,
                              hipStream_t stream) {
  (void)in_sizes; (void)n_in; (void)out_size;
  const float* enc   = (const float*)d_in[0];
  const int*   toks  = (const int*)  d_in[1];
  const float* table = (const float*)d_in[4];
  const float* sa_w  = (const float*)d_in[5];
  const float* sa_b  = (const float*)d_in[6];
  const float* ca_w  = (const float*)d_in[7];
  const float* ca_b  = (const float*)d_in[8];
  const float* f1w   = (const float*)d_in[9];
  const float* f1b   = (const float*)d_in[10];
  const float* f2w   = (const float*)d_in[11];
  const float* f2b   = (const float*)d_in[12];
  const float* lng   = (const float*)d_in[13];
  const float* lnbp  = (const float*)d_in[14];
  const float* fg    = (const float*)d_in[15];
  const float* fbp   = (const float*)d_in[16];
  float* outp = (float*)d_out;

  char* base = (char*)d_ws;
  size_t off = 0;
  auto alloc = [&](size_t nbytes) -> char* {
    char* p = base + off;
    off += (nbytes + 255) & ~(size_t)255;
    return p;
  };
  const size_t DDb = (size_t)DM * DM;
  bf16* wt_sa   = (bf16*)alloc((size_t)NL * 4 * DDb * 2);
  bf16* wt_ca   = (bf16*)alloc((size_t)NL * 4 * DDb * 2);
  bf16* wt_f1   = (bf16*)alloc((size_t)NL * FF * DM * 2);
  bf16* wt_f2   = (bf16*)alloc((size_t)NL * FF * DM * 2);
  bf16* encb    = (bf16*)alloc((size_t)NTOK * DM * 2);
  bf16* keall   = (bf16*)alloc((size_t)NTOK * NL * DM * 2);   // [4096][6144]
  bf16* vteall  = (bf16*)alloc((size_t)NL * DM * NTOK * 2);   // [6144][4096]
  bf16* hbuf    = (bf16*)alloc((size_t)NTOK * DM * 2);
  bf16* qkbuf   = (bf16*)alloc((size_t)NTOK * 2 * DM * 2);    // fused Q|K (stride 2048)
  bf16* vtbuf   = (bf16*)alloc((size_t)NTOK * DM * 2);
  bf16* aobuf   = (bf16*)alloc((size_t)NTOK * DM * 2);
  bf16* h1buf   = (bf16*)alloc((size_t)NTOK * FF * 2);
  float* xbuf   = (float*)alloc((size_t)NTOK * DM * 4);
  if (off > ws_size) return;
  // split-K partials alias dead self-attn buffers during FFN2:
  // qkbuf(16MB)+vtbuf(8MB)+aobuf(8MB) = 32MB contiguous = 2 x [NTOK x DM] f32
  float* pbuf = (float*)qkbuf;

  dim3 tb(32, 8);
  transpose_cvt<<<dim3(DM/32, DM/32, NL*4), tb, 0, stream>>>(sa_w, wt_sa, DM, DM);
  transpose_cvt<<<dim3(DM/32, DM/32, NL*4), tb, 0, stream>>>(ca_w, wt_ca, DM, DM);
  transpose_cvt<<<dim3(FF/32, DM/32, NL),   tb, 0, stream>>>(f1w, wt_f1, DM, FF);
  transpose_cvt<<<dim3(DM/32, FF/32, NL),   tb, 0, stream>>>(f2w, wt_f2, FF, DM);
  cvt_bf16<<<(NTOK * DM / 4) / 256, 256, 0, stream>>>(enc, encb);
  embed_pe<<<NTOK, 256, 0, stream>>>(toks, table, xbuf);

  // hoisted: all-layer encoder K projection and V^T projection (1536 blocks each)
  gemm_bt<5,128><<<dim3(NL*DM/128, NTOK/128), 256, 0, stream>>>(encb, wt_ca, ca_b, keall, nullptr, NTOK, NL*DM, DM);
  gemm_bt<6,128><<<dim3(NTOK/128, NL*DM/128), 256, 0, stream>>>(wt_ca, encb, ca_b, vteall, nullptr, NL*DM, NTOK, DM);

  // layer-0 pre-norm (subsequent ones fused into the FFN2 reduce)
  ln_kernel<0><<<NTOK, 256, 0, stream>>>(xbuf, lng + 0*DM, lnbp + 0*DM, hbuf, nullptr);

  for (int l = 0; l < NL; ++l) {
    const bf16* wsa = wt_sa + (size_t)l * 4 * DDb;
    const bf16* wca = wt_ca + (size_t)l * 4 * DDb;
    const float* bsa = sa_b + (size_t)l * 4 * DM;
    const float* bca = ca_b + (size_t)l * 4 * DM;
    // ---- self-attention (pre-norm output already in hbuf) ----
    gemm_bt<0,128><<<dim3(2*DM/128, NTOK/128), 256, 0, stream>>>(hbuf, wsa + 0*DDb, bsa + 0*DM, qkbuf, nullptr, NTOK, 2*DM, DM);
    gemm_bt<2,64><<<dim3(NTOK/64, DM/128), 256, 0, stream>>>(wsa + 2*DDb, hbuf, bsa + 2*DM, vtbuf, nullptr, DM, NTOK, DM);
    attn_kernel<1><<<dim3(SEQL/64, NB_*NH), 256, 0, stream>>>(qkbuf, qkbuf + DM, vtbuf, aobuf, 2*DM, 2*DM);
    gemm_bt<3,64><<<dim3(DM/64, NTOK/128), 256, 0, stream>>>(aobuf, wsa + 3*DDb, bsa + 3*DM, nullptr, xbuf, NTOK, DM, DM);
    // ---- cross-attention (pre-norm) ----
    ln_kernel<0><<<NTOK, 256, 0, stream>>>(xbuf, lng + (l*3+1)*DM, lnbp + (l*3+1)*DM, hbuf, nullptr);
    gemm_bt<0,64><<<dim3(DM/64, NTOK/128), 256, 0, stream>>>(hbuf, wca + 0*DDb, bca + 0*DM, qkbuf, nullptr, NTOK, DM, DM);
    attn_kernel<0><<<dim3(SEQL/64, NB_*NH), 256, 0, stream>>>(qkbuf, keall + l*DM, vteall + (size_t)l*DM*NTOK, aobuf, DM, NL*DM);
    gemm_bt<3,64><<<dim3(DM/64, NTOK/128), 256, 0, stream>>>(aobuf, wca + 3*DDb, bca + 3*DM, nullptr, xbuf, NTOK, DM, DM);
    // ---- FFN (pre-norm) ----
    ln_kernel<0><<<NTOK, 256, 0, stream>>>(xbuf, lng + (l*3+2)*DM, lnbp + (l*3+2)*DM, hbuf, nullptr);
    gemm_bt<1,128><<<dim3(FF/128, NTOK/128), 256, 0, stream>>>(hbuf, wt_f1 + (size_t)l*FF*DM, f1b + (size_t)l*FF, h1buf, nullptr, NTOK, FF, DM);
    gemm_bt<4,64><<<dim3(DM/64, NTOK/128, 2), 256, 0, stream>>>(h1buf, wt_f2 + (size_t)l*FF*DM, nullptr, nullptr, pbuf, NTOK, DM, FF);
    if (l < NL - 1)
      ln_fused<0><<<NTOK, 256, 0, stream>>>(xbuf, pbuf, pbuf + (size_t)NTOK*DM, f2b + (size_t)l*DM,
                                            lng + ((l+1)*3+0)*DM, lnbp + ((l+1)*3+0)*DM, hbuf, nullptr);
    else
      ln_fused<1><<<NTOK, 256, 0, stream>>>(xbuf, pbuf, pbuf + (size_t)NTOK*DM, f2b + (size_t)l*DM,
                                            fg, fbp, nullptr, outp);
  }
}